// Round 5
// baseline (377.587 us; speedup 1.0000x reference)
//
#include <hip/hip_runtime.h>

#define N_NODES 100000
#define E_EDGES 1600000
#define EP      (E_EDGES + N_NODES)   // edges + self loops = 1,700,000
#define P_CAND  262144
#define IN_C    128
#define HID     64
#define NEG_SLOPE 0.2f

#define NBIN  196            // ceil(100000/512) bins of 512 nodes
#define NB2   256            // blocks for hist/scatterbin
#define EPB   ((EP + NB2 - 1) / NB2)   // 6641 edges per block
#define NTOT  (NBIN * NB2)   // 50176 (= 1024*49)

typedef _Float16 half4v __attribute__((ext_vector_type(4)));
typedef _Float16 half8v __attribute__((ext_vector_type(8)));
typedef float    float4v __attribute__((ext_vector_type(4)));

// ---------------- CSR build: deterministic 2-level counting sort ----------------

__global__ __launch_bounds__(256) void hist_kernel(const int* __restrict__ ei,
                                                   int* __restrict__ hist) {
    __shared__ int lh[NBIN];
    for (int t = threadIdx.x; t < NBIN; t += 256) lh[t] = 0;
    __syncthreads();
    int start = blockIdx.x * EPB;
    int end = min(start + EPB, EP);
    for (int i = start + threadIdx.x; i < end; i += 256) {
        int dst = (i < E_EDGES) ? ei[E_EDGES + i] : (i - E_EDGES);
        atomicAdd(&lh[dst >> 9], 1);
    }
    __syncthreads();
    for (int t = threadIdx.x; t < NBIN; t += 256) hist[t * NB2 + blockIdx.x] = lh[t];
}

__global__ __launch_bounds__(1024) void scan2_kernel(const int* __restrict__ hist,
                                                     int* __restrict__ histS) {
    __shared__ int s[1024];
    int t = threadIdx.x;
    int b0 = t * 49;                       // 1024*49 == 50176
    int sum = 0;
    for (int i = 0; i < 49; i++) sum += hist[b0 + i];
    s[t] = sum;
    __syncthreads();
    for (int d = 1; d < 1024; d <<= 1) {
        int v = (t >= d) ? s[t - d] : 0;
        __syncthreads();
        s[t] += v;
        __syncthreads();
    }
    int run = s[t] - sum;
    for (int i = 0; i < 49; i++) { int hv = hist[b0 + i]; histS[b0 + i] = run; run += hv; }
}

__global__ __launch_bounds__(256) void scatterbin_kernel(const int* __restrict__ ei,
                                                         const int* __restrict__ histS,
                                                         unsigned* __restrict__ binned) {
    __shared__ int cur[NBIN];
    for (int t = threadIdx.x; t < NBIN; t += 256) cur[t] = histS[t * NB2 + blockIdx.x];
    __syncthreads();
    int start = blockIdx.x * EPB;
    int end = min(start + EPB, EP);
    for (int i = start + threadIdx.x; i < end; i += 256) {
        int src, dst;
        if (i < E_EDGES) { src = ei[i]; dst = ei[E_EDGES + i]; }
        else             { src = i - E_EDGES; dst = src; }
        int pos = atomicAdd(&cur[dst >> 9], 1);
        binned[pos] = (unsigned)src | ((unsigned)(dst & 511) << 17);
    }
}

__global__ __launch_bounds__(1024) void binsort_kernel(const unsigned* __restrict__ binned,
                                                       const int* __restrict__ histS,
                                                       int* __restrict__ off,
                                                       int* __restrict__ csr) {
    __shared__ int lh[512];
    __shared__ int lsc[512];
    int b = blockIdx.x, t = threadIdx.x;
    int base = histS[b * NB2];
    int endv = (b == NBIN - 1) ? EP : histS[(b + 1) * NB2];
    if (t < 512) lh[t] = 0;
    __syncthreads();
    for (int i = base + t; i < endv; i += 1024)
        atomicAdd(&lh[binned[i] >> 17], 1);
    __syncthreads();
    if (t < 512) lsc[t] = lh[t];
    __syncthreads();
    for (int d = 1; d < 512; d <<= 1) {
        int v = (t >= d && t < 512) ? lsc[t - d] : 0;
        __syncthreads();
        if (t < 512) lsc[t] += v;
        __syncthreads();
    }
    if (t < 512) {
        int ex = lsc[t] - lh[t];
        int node = b * 512 + t;
        if (node <= N_NODES) off[node] = base + ex;
        lh[t] = base + ex;
    }
    __syncthreads();
    for (int i = base + t; i < endv; i += 1024) {
        unsigned v = binned[i];
        int pos = atomicAdd(&lh[v >> 17], 1);
        csr[pos] = (int)(v & 0x1FFFFu);
    }
}

// ---- Weight prep: fp16 transposed copies + folded attention columns W·a ----
// W1T layout: [col][k], col 0..143 (128 real, 4 att-dot cols, 12 zero pad)
// W2T layout: [col][k], col 0..79  (64 real, 2 att-dot cols, 14 zero pad)

__global__ __launch_bounds__(256) void prep_kernel(
        const float* __restrict__ W1, const float* __restrict__ W2,
        const float* __restrict__ att_src1, const float* __restrict__ att_dst1,
        const float* __restrict__ att_src2, const float* __restrict__ att_dst2,
        _Float16* __restrict__ W1T, _Float16* __restrict__ W2T) {
    int idx = blockIdx.x * 256 + threadIdx.x;
    if (idx < 16384) {
        int col = idx >> 7, k = idx & 127;
        W1T[idx] = (_Float16)W1[k * 128 + col];
    } else if (idx < 16896) {
        int j = idx - 16384;
        int c4 = j >> 7, k = j & 127;   // c4: 0=as_h0 1=as_h1 2=ad_h0 3=ad_h1
        const float* av = (c4 < 2 ? att_src1 : att_dst1) + (c4 & 1) * 64;
        const float* wr = W1 + k * 128 + (c4 & 1) * 64;
        float s = 0.f;
        for (int c = 0; c < 64; c++) s += wr[c] * av[c];
        W1T[(128 + c4) * 128 + k] = (_Float16)s;
    } else if (idx < 18432) {
        W1T[132 * 128 + (idx - 16896)] = (_Float16)0.f;
    } else if (idx < 26624) {
        int j = idx - 18432;
        int col = j >> 7, k = j & 127;
        W2T[col * 128 + k] = (_Float16)W2[k * 64 + col];
    } else if (idx < 26880) {
        int j = idx - 26624;
        int c2 = j >> 7, k = j & 127;   // 0=as2 1=ad2
        const float* av = c2 ? att_dst2 : att_src2;
        const float* wr = W2 + k * 64;
        float s = 0.f;
        for (int c = 0; c < 64; c++) s += wr[c] * av[c];
        W2T[(64 + c2) * 128 + k] = (_Float16)s;
    } else if (idx < 28672) {
        W2T[66 * 128 + (idx - 26880)] = (_Float16)0.f;
    }
}

// -------- Layer 1 GEMM: direct-to-register fragments, att folded into MFMA --------

__global__ __launch_bounds__(256) void gemm1_kernel(
        const float* __restrict__ x, const _Float16* __restrict__ W1T,
        _Float16* __restrict__ xw1h, float* __restrict__ as1, float* __restrict__ ad1) {
    __shared__ _Float16 xs[64 * 136];       // output transpose only
    int tid = threadIdx.x;
    int base = blockIdx.x * 64;
    int w = tid >> 6, l = tid & 63;
    int quad = l >> 4, lq = l & 15;
    int row = base + 16 * w + lq;
    size_t rb = (size_t)(row < N_NODES ? row : 0) * 32;   // float4 units
    const float4* x4 = (const float4*)x;
    // A fragments: 8 independent dwordx4 loads, deep MLP
    float4 af[8];
#pragma unroll
    for (int ks = 0; ks < 4; ks++) {
        af[2 * ks]     = x4[rb + ks * 8 + quad * 2];
        af[2 * ks + 1] = x4[rb + ks * 8 + quad * 2 + 1];
    }
    half8v a[4];
#pragma unroll
    for (int ks = 0; ks < 4; ks++) {
        float4 u0 = af[2 * ks], u1 = af[2 * ks + 1];
        half8v t;
        t[0] = (_Float16)u0.x; t[1] = (_Float16)u0.y; t[2] = (_Float16)u0.z; t[3] = (_Float16)u0.w;
        t[4] = (_Float16)u1.x; t[5] = (_Float16)u1.y; t[6] = (_Float16)u1.z; t[7] = (_Float16)u1.w;
        a[ks] = t;
    }
    float4v acc[9];
#pragma unroll
    for (int t = 0; t < 9; t++) acc[t] = (float4v)0.f;
#pragma unroll
    for (int ks = 0; ks < 4; ++ks) {
#pragma unroll
        for (int t = 0; t < 9; t++) {
            half8v b = *(const half8v*)&W1T[(t * 16 + lq) * 128 + ks * 32 + quad * 8];
            acc[t] = __builtin_amdgcn_mfma_f32_16x16x32_f16(a[ks], b, acc[t], 0, 0, 0);
        }
    }
    // attention dots came out of MFMA tile t=8 (cols 128..131), lanes lq 0..3
    if (lq < 4) {
        float* dst = (lq < 2) ? as1 : ad1;
        int hsel = lq & 1;
#pragma unroll
        for (int r = 0; r < 4; r++) {
            int n = base + 16 * w + quad * 4 + r;
            if (n < N_NODES) dst[2 * n + hsel] = acc[8][r];
        }
    }
    // transpose via LDS, coalesced fp16 write
#pragma unroll
    for (int t = 0; t < 8; t++)
#pragma unroll
        for (int r = 0; r < 4; r++)
            xs[(16 * w + quad * 4 + r) * 136 + t * 16 + lq] = (_Float16)acc[t][r];
    __syncthreads();
    int node = tid >> 2, seg = tid & 3;
    if (base + node < N_NODES) {
#pragma unroll
        for (int i = 0; i < 4; i++) {
            half8v vv = *(const half8v*)&xs[node * 136 + seg * 32 + i * 8];
            *(half8v*)&xw1h[(size_t)(base + node) * 128 + seg * 32 + i * 8] = vv;
        }
    }
}

// ---- Layer 1 aggregation: static double-buffered windows, f=0 sentinel, no rotation ----

__global__ __launch_bounds__(256) void agg1_kernel(
        const int* __restrict__ off, const int* __restrict__ csr_src,
        const float* __restrict__ as1, const float* __restrict__ ad1,
        const _Float16* __restrict__ xw1h, const float* __restrict__ b1,
        _Float16* __restrict__ h) {
    __shared__ float2 esm[4][64];           // per-wave (f0, f1); zeros beyond cnt
    int wv = threadIdx.x >> 6, lane = threadIdx.x & 63;
    int n = blockIdx.x * 4 + wv;
    if (n >= N_NODES) return;
    int s = off[n], e = off[n + 1];
    float adn0 = ad1[2 * n], adn1 = ad1[2 * n + 1];
    int e4 = lane >> 4, q = lane & 15;      // edge-slot group 0..3; cols 8q..8q+7 (q<8:head0)
    // per-lane f pointer: slot stride 8B, head select folded in once
    const char* fl = (const char*)&esm[wv][e4] + ((q >= 8) ? 4 : 0);
    float acc[8];
#pragma unroll
    for (int i = 0; i < 8; i++) acc[i] = 0.f;
    float sl0 = 0.f, sl1 = 0.f;             // per-lane denominator partials

#define LD1(j) ({ int jc_ = (j) < cnt ? (j) : cnt - 1;                     \
                  int sv_ = __shfl(srcv, jc_);                             \
                  *(const half8v*)&xw1h[(size_t)sv_ * 128 + 8 * q]; })
#define FMA1(R, F) { _Pragma("unroll")                                     \
    for (int i_ = 0; i_ < 8; i_++) acc[i_] = fmaf((float)R[i_], (F), acc[i_]); }

    for (int b = s; b < e; b += 64) {
        int cnt = min(64, e - b);
        int l = lane < cnt ? lane : cnt - 1;
        int srcv = csr_src[b + l];
        // preload window A (slots 0..15) — flies under the expf chain below
        half8v A0 = (half8v)(_Float16)0.f, A1 = A0, A2 = A0, A3 = A0;
        half8v B0 = A0, B1 = A0, B2 = A0, B3 = A0;
        A0 = LD1(e4);
        if (4  < cnt) A1 = LD1(4 + e4);
        if (8  < cnt) A2 = LD1(8 + e4);
        if (12 < cnt) A3 = LD1(12 + e4);
        float2 a = *(const float2*)&as1[2 * srcv];
        float e0 = a.x + adn0; e0 = e0 > 0.f ? e0 : NEG_SLOPE * e0;
        float e1 = a.y + adn1; e1 = e1 > 0.f ? e1 : NEG_SLOPE * e1;
        float f0v = (lane < cnt) ? __expf(e0) : 0.f;
        float f1v = (lane < cnt) ? __expf(e1) : 0.f;
        esm[wv][lane] = make_float2(f0v, f1v);
        sl0 += f0v; sl1 += f1v;
        int jj = 0;
        for (;;) {
            bool moreB = jj + 16 < cnt;
            if (moreB)         B0 = LD1(jj + 16 + e4);
            if (jj + 20 < cnt) B1 = LD1(jj + 20 + e4);
            if (jj + 24 < cnt) B2 = LD1(jj + 24 + e4);
            if (jj + 28 < cnt) B3 = LD1(jj + 28 + e4);
            { float f = *(const float*)(fl + (size_t)jj * 8);        FMA1(A0, f) }
            if (jj + 4  < cnt) { float f = *(const float*)(fl + (size_t)(jj + 4)  * 8); FMA1(A1, f) }
            if (jj + 8  < cnt) { float f = *(const float*)(fl + (size_t)(jj + 8)  * 8); FMA1(A2, f) }
            if (jj + 12 < cnt) { float f = *(const float*)(fl + (size_t)(jj + 12) * 8); FMA1(A3, f) }
            jj += 16;
            if (!moreB) break;
            bool moreA = jj + 16 < cnt;
            if (moreA)         A0 = LD1(jj + 16 + e4);
            if (jj + 20 < cnt) A1 = LD1(jj + 20 + e4);
            if (jj + 24 < cnt) A2 = LD1(jj + 24 + e4);
            if (jj + 28 < cnt) A3 = LD1(jj + 28 + e4);
            { float f = *(const float*)(fl + (size_t)jj * 8);        FMA1(B0, f) }
            if (jj + 4  < cnt) { float f = *(const float*)(fl + (size_t)(jj + 4)  * 8); FMA1(B1, f) }
            if (jj + 8  < cnt) { float f = *(const float*)(fl + (size_t)(jj + 8)  * 8); FMA1(B2, f) }
            if (jj + 12 < cnt) { float f = *(const float*)(fl + (size_t)(jj + 12) * 8); FMA1(B3, f) }
            jj += 16;
            if (!moreA) break;
        }
    }
#undef LD1
#pragma unroll
    for (int m = 32; m >= 1; m >>= 1) { sl0 += __shfl_xor(sl0, m); sl1 += __shfl_xor(sl1, m); }
#pragma unroll
    for (int m = 32; m >= 16; m >>= 1) {
#pragma unroll
        for (int i = 0; i < 8; i++) acc[i] += __shfl_xor(acc[i], m);
    }
    if (lane < 16) {
        float sum = (q >= 8) ? sl1 : sl0;
        float rs = __builtin_amdgcn_rcpf(sum);   // ~1 ulp, << fp16 storage error
        int c = 8 * q;
        half8v o;
#pragma unroll
        for (int i = 0; i < 8; i++) {
            float vv = fmaf(acc[i], rs, b1[c + i]);
            o[i] = (_Float16)(vv > 0.f ? vv : 0.f);   // relu
        }
        *(half8v*)&h[(size_t)n * 128 + c] = o;
    }
}

// -------- Layer 2 GEMM: direct-to-register fp16 fragments, att folded --------

__global__ __launch_bounds__(256) void gemm2_kernel(
        const _Float16* __restrict__ h, const _Float16* __restrict__ W2T,
        _Float16* __restrict__ xw2h, float* __restrict__ as2, float* __restrict__ ad2) {
    __shared__ _Float16 xs[64 * 72];        // output transpose only
    int tid = threadIdx.x;
    int base = blockIdx.x * 64;
    int w = tid >> 6, l = tid & 63;
    int quad = l >> 4, lq = l & 15;
    int row = base + 16 * w + lq;
    size_t rbase = (size_t)(row < N_NODES ? row : 0) * 128;
    half8v a[4];
#pragma unroll
    for (int ks = 0; ks < 4; ks++)
        a[ks] = *(const half8v*)&h[rbase + ks * 32 + quad * 8];
    float4v acc[5];
#pragma unroll
    for (int t = 0; t < 5; t++) acc[t] = (float4v)0.f;
#pragma unroll
    for (int ks = 0; ks < 4; ++ks) {
#pragma unroll
        for (int t = 0; t < 5; t++) {
            half8v b = *(const half8v*)&W2T[(t * 16 + lq) * 128 + ks * 32 + quad * 8];
            acc[t] = __builtin_amdgcn_mfma_f32_16x16x32_f16(a[ks], b, acc[t], 0, 0, 0);
        }
    }
    // attention dots from MFMA tile t=4 (cols 64,65), lanes lq 0..1
    if (lq < 2) {
        float* dst = lq ? ad2 : as2;
#pragma unroll
        for (int r = 0; r < 4; r++) {
            int n = base + 16 * w + quad * 4 + r;
            if (n < N_NODES) dst[n] = acc[4][r];
        }
    }
#pragma unroll
    for (int t = 0; t < 4; t++)
#pragma unroll
        for (int r = 0; r < 4; r++)
            xs[(16 * w + quad * 4 + r) * 72 + t * 16 + lq] = (_Float16)acc[t][r];
    __syncthreads();
    int node = tid >> 2, seg = tid & 3;
    if (base + node < N_NODES) {
#pragma unroll
        for (int i = 0; i < 2; i++) {
            half8v vv = *(const half8v*)&xs[node * 72 + seg * 16 + i * 8];
            *(half8v*)&xw2h[(size_t)(base + node) * 64 + seg * 16 + i * 8] = vv;
        }
    }
}

// ---- Layer 2 aggregation: static double-buffered windows, f=0 sentinel ----

__global__ __launch_bounds__(256) void agg2_kernel(
        const int* __restrict__ off, const int* __restrict__ csr_src,
        const float* __restrict__ as2, const float* __restrict__ ad2,
        const _Float16* __restrict__ xw2h, const float* __restrict__ b2,
        const float* __restrict__ lw, float* __restrict__ u, float* __restrict__ v) {
    __shared__ float esm[4][64];            // per-wave f; zeros beyond cnt
    int wv = threadIdx.x >> 6, lane = threadIdx.x & 63;
    int n = blockIdx.x * 4 + wv;
    if (n >= N_NODES) return;
    int s = off[n], e = off[n + 1];
    float adn = ad2[n];
    int e8 = lane >> 3, q = lane & 7;       // edge-slot group 0..7; cols 8q..8q+7
    const float* fl = &esm[wv][e8];
    float acc[8];
#pragma unroll
    for (int i = 0; i < 8; i++) acc[i] = 0.f;
    float sl = 0.f;

#define LD2(j) ({ int jc_ = (j) < cnt ? (j) : cnt - 1;                     \
                  int sv_ = __shfl(srcv, jc_);                             \
                  *(const half8v*)&xw2h[(size_t)sv_ * 64 + 8 * q]; })
#define FMA2(R, F) { _Pragma("unroll")                                     \
    for (int i_ = 0; i_ < 8; i_++) acc[i_] = fmaf((float)R[i_], (F), acc[i_]); }

    for (int b = s; b < e; b += 64) {
        int cnt = min(64, e - b);
        int l = lane < cnt ? lane : cnt - 1;
        int srcv = csr_src[b + l];
        half8v A0 = (half8v)(_Float16)0.f, A1 = A0, B0 = A0, B1 = A0;
        A0 = LD2(e8);
        if (8 < cnt) A1 = LD2(8 + e8);
        float a = as2[srcv];
        float ev = a + adn; ev = ev > 0.f ? ev : NEG_SLOPE * ev;
        float fv = (lane < cnt) ? __expf(ev) : 0.f;
        esm[wv][lane] = fv;
        sl += fv;
        int jj = 0;
        for (;;) {
            bool moreB = jj + 16 < cnt;
            if (moreB)         B0 = LD2(jj + 16 + e8);
            if (jj + 24 < cnt) B1 = LD2(jj + 24 + e8);
            { float f = fl[jj];                      FMA2(A0, f) }
            if (jj + 8 < cnt) { float f = fl[jj + 8]; FMA2(A1, f) }
            jj += 16;
            if (!moreB) break;
            bool moreA = jj + 16 < cnt;
            if (moreA)         A0 = LD2(jj + 16 + e8);
            if (jj + 24 < cnt) A1 = LD2(jj + 24 + e8);
            { float f = fl[jj];                      FMA2(B0, f) }
            if (jj + 8 < cnt) { float f = fl[jj + 8]; FMA2(B1, f) }
            jj += 16;
            if (!moreA) break;
        }
    }
#undef LD2
#pragma unroll
    for (int m = 32; m >= 1; m >>= 1) sl += __shfl_xor(sl, m);
#pragma unroll
    for (int m = 32; m >= 8; m >>= 1) {
#pragma unroll
        for (int i = 0; i < 8; i++) acc[i] += __shfl_xor(acc[i], m);
    }
    int c = 8 * q;
    float rs = __builtin_amdgcn_rcpf(sl);
    float pu = 0.f, pv = 0.f;
#pragma unroll
    for (int i = 0; i < 8; i++) {
        float zi = fmaf(acc[i], rs, b2[c + i]);
        pu = fmaf(zi, lw[c + i], pu);
        pv = fmaf(zi, lw[64 + c + i], pv);
    }
#pragma unroll
    for (int m = 4; m >= 1; m >>= 1) {
        pu += __shfl_xor(pu, m);
        pv += __shfl_xor(pv, m);
    }
    if (lane == 0) { u[n] = pu; v[n] = pv; }
}

// ---------------- Link decode: out = u[s] + v[d] + lb ----------------

__global__ __launch_bounds__(256) void decode_kernel(
        const int* __restrict__ pos_ei, const int* __restrict__ neg_ei,
        const float* __restrict__ u, const float* __restrict__ v,
        const float* __restrict__ lb, float* __restrict__ out) {
    int idx = blockIdx.x * 256 + threadIdx.x;
    if (idx >= 2 * P_CAND) return;
    const int* ei; int p;
    if (idx < P_CAND) { ei = pos_ei; p = idx; }
    else              { ei = neg_ei; p = idx - P_CAND; }
    int sN = ei[p], dN = ei[P_CAND + p];
    out[idx] = u[sN] + v[dN] + lb[0];
}

// ---------------- launch ----------------

extern "C" void kernel_launch(void* const* d_in, const int* in_sizes, int n_in,
                              void* d_out, int out_size, void* d_ws, size_t ws_size,
                              hipStream_t stream) {
    const float* x        = (const float*)d_in[0];
    const int*   ei       = (const int*)d_in[1];
    const int*   pos_ei   = (const int*)d_in[3];
    const int*   neg_ei   = (const int*)d_in[4];
    const float* W1       = (const float*)d_in[5];
    const float* att_src1 = (const float*)d_in[6];
    const float* att_dst1 = (const float*)d_in[7];
    const float* b1       = (const float*)d_in[8];
    const float* W2       = (const float*)d_in[9];
    const float* att_src2 = (const float*)d_in[10];
    const float* att_dst2 = (const float*)d_in[11];
    const float* b2       = (const float*)d_in[12];
    const float* lw       = (const float*)d_in[13];
    const float* lb       = (const float*)d_in[14];
    float* out = (float*)d_out;

    char* ws = (char*)d_ws;
    size_t o = 0;
    auto alloc = [&](size_t bytes) -> char* {
        char* p = ws + o;
        o += (bytes + 511) & ~(size_t)511;
        return p;
    };
    _Float16* xw1h  = (_Float16*)alloc((size_t)N_NODES * 128 * 2);  // reused: xw2h
    _Float16* h     = (_Float16*)alloc((size_t)N_NODES * 128 * 2 + 16384); // +slack for OOB-safe reads
    float*    u     = (float*)alloc((size_t)N_NODES * 4);
    float*    v     = (float*)alloc((size_t)N_NODES * 4);
    float*    as1   = (float*)alloc((size_t)N_NODES * 2 * 4);
    float*    ad1   = (float*)alloc((size_t)N_NODES * 2 * 4);
    float*    as2   = (float*)alloc((size_t)N_NODES * 4);
    float*    ad2   = (float*)alloc((size_t)N_NODES * 4);
    int*      off   = (int*)alloc((size_t)(N_NODES + 1) * 4);
    int*      hist  = (int*)alloc((size_t)NTOT * 4);
    int*      histS = (int*)alloc((size_t)NTOT * 4);
    unsigned* binned= (unsigned*)alloc((size_t)EP * 4);
    int*      csr   = (int*)alloc((size_t)EP * 4);
    _Float16* W1T   = (_Float16*)alloc((size_t)144 * 128 * 2);  // 128 cols + 4 att cols + 12 zero
    _Float16* W2T   = (_Float16*)alloc((size_t)80 * 128 * 2);   // 64 cols + 2 att cols + 14 zero
    _Float16* xw2h  = xw1h;    // xw1h dead after agg1

    prep_kernel<<<112, 256, 0, stream>>>(W1, W2, att_src1, att_dst1, att_src2, att_dst2, W1T, W2T);
    hist_kernel<<<NB2, 256, 0, stream>>>(ei, hist);
    scan2_kernel<<<1, 1024, 0, stream>>>(hist, histS);
    scatterbin_kernel<<<NB2, 256, 0, stream>>>(ei, histS, binned);
    binsort_kernel<<<NBIN, 1024, 0, stream>>>(binned, histS, off, csr);
    gemm1_kernel<<<(N_NODES + 63) / 64, 256, 0, stream>>>(x, W1T, xw1h, as1, ad1);
    agg1_kernel<<<(N_NODES + 3) / 4, 256, 0, stream>>>(off, csr, as1, ad1, xw1h, b1, h);
    gemm2_kernel<<<(N_NODES + 63) / 64, 256, 0, stream>>>(h, W2T, xw2h, as2, ad2);
    agg2_kernel<<<(N_NODES + 3) / 4, 256, 0, stream>>>(off, csr, as2, ad2, xw2h, b2, lw, u, v);
    decode_kernel<<<(2 * P_CAND + 255) / 256, 256, 0, stream>>>(pos_ei, neg_ei, u, v, lb, out);
}

// Round 6
// 355.791 us; speedup vs baseline: 1.0613x; 1.0613x over previous
//
#include <hip/hip_runtime.h>

#define N_NODES 100000
#define E_EDGES 1600000
#define EP      (E_EDGES + N_NODES)   // edges + self loops = 1,700,000
#define P_CAND  262144
#define IN_C    128
#define HID     64
#define NEG_SLOPE 0.2f

#define NBIN  196            // ceil(100000/512) bins of 512 nodes
#define NB2   256            // blocks for hist/scatterbin
#define EPB   ((EP + NB2 - 1) / NB2)   // 6641 edges per block
#define NTOT  (NBIN * NB2)   // 50176 (= 1024*49)

typedef _Float16 half4v __attribute__((ext_vector_type(4)));
typedef _Float16 half8v __attribute__((ext_vector_type(8)));
typedef float    float4v __attribute__((ext_vector_type(4)));

// ---------------- CSR build: deterministic 2-level counting sort ----------------

__global__ __launch_bounds__(256) void hist_kernel(const int* __restrict__ ei,
                                                   int* __restrict__ hist) {
    __shared__ int lh[NBIN];
    for (int t = threadIdx.x; t < NBIN; t += 256) lh[t] = 0;
    __syncthreads();
    int start = blockIdx.x * EPB;
    int end = min(start + EPB, EP);
    for (int i = start + threadIdx.x; i < end; i += 256) {
        int dst = (i < E_EDGES) ? ei[E_EDGES + i] : (i - E_EDGES);
        atomicAdd(&lh[dst >> 9], 1);
    }
    __syncthreads();
    for (int t = threadIdx.x; t < NBIN; t += 256) hist[t * NB2 + blockIdx.x] = lh[t];
}

__global__ __launch_bounds__(1024) void scan2_kernel(const int* __restrict__ hist,
                                                     int* __restrict__ histS) {
    __shared__ int s[1024];
    int t = threadIdx.x;
    int b0 = t * 49;                       // 1024*49 == 50176
    int sum = 0;
    for (int i = 0; i < 49; i++) sum += hist[b0 + i];
    s[t] = sum;
    __syncthreads();
    for (int d = 1; d < 1024; d <<= 1) {
        int v = (t >= d) ? s[t - d] : 0;
        __syncthreads();
        s[t] += v;
        __syncthreads();
    }
    int run = s[t] - sum;
    for (int i = 0; i < 49; i++) { int hv = hist[b0 + i]; histS[b0 + i] = run; run += hv; }
}

__global__ __launch_bounds__(256) void scatterbin_kernel(const int* __restrict__ ei,
                                                         const int* __restrict__ histS,
                                                         unsigned* __restrict__ binned) {
    __shared__ int cur[NBIN];
    for (int t = threadIdx.x; t < NBIN; t += 256) cur[t] = histS[t * NB2 + blockIdx.x];
    __syncthreads();
    int start = blockIdx.x * EPB;
    int end = min(start + EPB, EP);
    for (int i = start + threadIdx.x; i < end; i += 256) {
        int src, dst;
        if (i < E_EDGES) { src = ei[i]; dst = ei[E_EDGES + i]; }
        else             { src = i - E_EDGES; dst = src; }
        int pos = atomicAdd(&cur[dst >> 9], 1);
        binned[pos] = (unsigned)src | ((unsigned)(dst & 511) << 17);
    }
}

__global__ __launch_bounds__(1024) void binsort_kernel(const unsigned* __restrict__ binned,
                                                       const int* __restrict__ histS,
                                                       int* __restrict__ off,
                                                       int* __restrict__ csr) {
    __shared__ int lh[512];
    __shared__ int lsc[512];
    int b = blockIdx.x, t = threadIdx.x;
    int base = histS[b * NB2];
    int endv = (b == NBIN - 1) ? EP : histS[(b + 1) * NB2];
    if (t < 512) lh[t] = 0;
    __syncthreads();
    for (int i = base + t; i < endv; i += 1024)
        atomicAdd(&lh[binned[i] >> 17], 1);
    __syncthreads();
    if (t < 512) lsc[t] = lh[t];
    __syncthreads();
    for (int d = 1; d < 512; d <<= 1) {
        int v = (t >= d && t < 512) ? lsc[t - d] : 0;
        __syncthreads();
        if (t < 512) lsc[t] += v;
        __syncthreads();
    }
    if (t < 512) {
        int ex = lsc[t] - lh[t];
        int node = b * 512 + t;
        if (node <= N_NODES) off[node] = base + ex;
        lh[t] = base + ex;
    }
    __syncthreads();
    for (int i = base + t; i < endv; i += 1024) {
        unsigned v = binned[i];
        int pos = atomicAdd(&lh[v >> 17], 1);
        csr[pos] = (int)(v & 0x1FFFFu);
    }
}

// ---- Weight prep: fp16 transposed copies + folded attention columns W·a ----
// W1T layout: [col][k], col 0..143 (128 real, 4 att-dot cols, 12 zero pad)
// W2T layout: [col][k], col 0..79  (64 real, 2 att-dot cols, 14 zero pad)

__global__ __launch_bounds__(256) void prep_kernel(
        const float* __restrict__ W1, const float* __restrict__ W2,
        const float* __restrict__ att_src1, const float* __restrict__ att_dst1,
        const float* __restrict__ att_src2, const float* __restrict__ att_dst2,
        _Float16* __restrict__ W1T, _Float16* __restrict__ W2T) {
    int idx = blockIdx.x * 256 + threadIdx.x;
    if (idx < 16384) {
        int col = idx >> 7, k = idx & 127;
        W1T[idx] = (_Float16)W1[k * 128 + col];
    } else if (idx < 16896) {
        int j = idx - 16384;
        int c4 = j >> 7, k = j & 127;   // c4: 0=as_h0 1=as_h1 2=ad_h0 3=ad_h1
        const float* av = (c4 < 2 ? att_src1 : att_dst1) + (c4 & 1) * 64;
        const float* wr = W1 + k * 128 + (c4 & 1) * 64;
        float s = 0.f;
        for (int c = 0; c < 64; c++) s += wr[c] * av[c];
        W1T[(128 + c4) * 128 + k] = (_Float16)s;
    } else if (idx < 18432) {
        W1T[132 * 128 + (idx - 16896)] = (_Float16)0.f;
    } else if (idx < 26624) {
        int j = idx - 18432;
        int col = j >> 7, k = j & 127;
        W2T[col * 128 + k] = (_Float16)W2[k * 64 + col];
    } else if (idx < 26880) {
        int j = idx - 26624;
        int c2 = j >> 7, k = j & 127;   // 0=as2 1=ad2
        const float* av = c2 ? att_dst2 : att_src2;
        const float* wr = W2 + k * 64;
        float s = 0.f;
        for (int c = 0; c < 64; c++) s += wr[c] * av[c];
        W2T[(64 + c2) * 128 + k] = (_Float16)s;
    } else if (idx < 28672) {
        W2T[66 * 128 + (idx - 26880)] = (_Float16)0.f;
    }
}

// -------- Layer 1 GEMM: direct-to-register fragments, att folded into MFMA --------

__global__ __launch_bounds__(256) void gemm1_kernel(
        const float* __restrict__ x, const _Float16* __restrict__ W1T,
        _Float16* __restrict__ xw1h, float* __restrict__ as1, float* __restrict__ ad1) {
    __shared__ _Float16 xs[64 * 136];       // output transpose only
    int tid = threadIdx.x;
    int base = blockIdx.x * 64;
    int w = tid >> 6, l = tid & 63;
    int quad = l >> 4, lq = l & 15;
    int row = base + 16 * w + lq;
    size_t rb = (size_t)(row < N_NODES ? row : 0) * 32;   // float4 units
    const float4* x4 = (const float4*)x;
    // A fragments: 8 independent dwordx4 loads, deep MLP
    float4 af[8];
#pragma unroll
    for (int ks = 0; ks < 4; ks++) {
        af[2 * ks]     = x4[rb + ks * 8 + quad * 2];
        af[2 * ks + 1] = x4[rb + ks * 8 + quad * 2 + 1];
    }
    half8v a[4];
#pragma unroll
    for (int ks = 0; ks < 4; ks++) {
        float4 u0 = af[2 * ks], u1 = af[2 * ks + 1];
        half8v t;
        t[0] = (_Float16)u0.x; t[1] = (_Float16)u0.y; t[2] = (_Float16)u0.z; t[3] = (_Float16)u0.w;
        t[4] = (_Float16)u1.x; t[5] = (_Float16)u1.y; t[6] = (_Float16)u1.z; t[7] = (_Float16)u1.w;
        a[ks] = t;
    }
    float4v acc[9];
#pragma unroll
    for (int t = 0; t < 9; t++) acc[t] = (float4v)0.f;
#pragma unroll
    for (int ks = 0; ks < 4; ++ks) {
#pragma unroll
        for (int t = 0; t < 9; t++) {
            half8v b = *(const half8v*)&W1T[(t * 16 + lq) * 128 + ks * 32 + quad * 8];
            acc[t] = __builtin_amdgcn_mfma_f32_16x16x32_f16(a[ks], b, acc[t], 0, 0, 0);
        }
    }
    // attention dots came out of MFMA tile t=8 (cols 128..131), lanes lq 0..3
    if (lq < 4) {
        float* dst = (lq < 2) ? as1 : ad1;
        int hsel = lq & 1;
#pragma unroll
        for (int r = 0; r < 4; r++) {
            int n = base + 16 * w + quad * 4 + r;
            if (n < N_NODES) dst[2 * n + hsel] = acc[8][r];
        }
    }
    // transpose via LDS, coalesced fp16 write
#pragma unroll
    for (int t = 0; t < 8; t++)
#pragma unroll
        for (int r = 0; r < 4; r++)
            xs[(16 * w + quad * 4 + r) * 136 + t * 16 + lq] = (_Float16)acc[t][r];
    __syncthreads();
    int node = tid >> 2, seg = tid & 3;
    if (base + node < N_NODES) {
#pragma unroll
        for (int i = 0; i < 4; i++) {
            half8v vv = *(const half8v*)&xs[node * 136 + seg * 32 + i * 8];
            *(half8v*)&xw1h[(size_t)(base + node) * 128 + seg * 32 + i * 8] = vv;
        }
    }
}

// ---- Layer 1 aggregation: one node per 16-lane group (4 nodes/wave) ----
// Each lane owns 8 output cols -> no accumulator butterfly; prologue 4x amortized.

__global__ __launch_bounds__(256) void agg1_kernel(
        const int* __restrict__ off, const int* __restrict__ csr_src,
        const float* __restrict__ as1, const float* __restrict__ ad1,
        const _Float16* __restrict__ xw1h, const float* __restrict__ b1,
        _Float16* __restrict__ h) {
    __shared__ float2 esm[4][64];           // per-wave (f0, f1) records
    int wv = threadIdx.x >> 6, lane = threadIdx.x & 63;
    int ql = lane & 15;                     // edge lane within group == col-group (ql<8: head0)
    int gb = lane & 48;                     // group base lane
    int n = blockIdx.x * 16 + (wv << 2) + (lane >> 4);   // 16 nodes/block, exact at 6250 blocks
    int s = off[n], e = off[n + 1];
    float adn0 = ad1[2 * n], adn1 = ad1[2 * n + 1];
    // per-lane f pointer: slot stride 8B within group, head select folded in once
    const char* fl = (const char*)&esm[wv][gb] + ((ql >= 8) ? 4 : 0);
    const _Float16* xq = xw1h + 8 * ql;     // col base folded into pointer
    float acc[8];
#pragma unroll
    for (int i = 0; i < 8; i++) acc[i] = 0.f;
    float sl0 = 0.f, sl1 = 0.f;             // per-lane denominator partials

#define FMA1(R, F) { _Pragma("unroll")                                     \
    for (int i_ = 0; i_ < 8; i_++) acc[i_] = fmaf((float)R[i_], (F), acc[i_]); }

    for (int b = s; b < e; b += 16) {
        int cnt = min(16, e - b);
        int l = ql < cnt ? ql : cnt - 1;
        int srcv = csr_src[b + l];
        float2 a = *(const float2*)&as1[2 * srcv];
        float e0 = a.x + adn0; e0 = e0 > 0.f ? e0 : NEG_SLOPE * e0;
        float e1 = a.y + adn1; e1 = e1 > 0.f ? e1 : NEG_SLOPE * e1;
        float f0v = (ql < cnt) ? __expf(e0) : 0.f;
        float f1v = (ql < cnt) ? __expf(e1) : 0.f;
        esm[wv][lane] = make_float2(f0v, f1v);
        sl0 += f0v; sl1 += f1v;
        // 2-deep rotation over this chunk's edges (group-uniform trip count)
        int sj = __shfl(srcv, gb);
        half8v cur = *(const half8v*)&xq[(size_t)sj * 128];
        int j = 0;
        for (; j + 1 < cnt; ++j) {
            int sn = __shfl(srcv, gb + j + 1);
            half8v nxt = *(const half8v*)&xq[(size_t)sn * 128];
            float f = *(const float*)(fl + (size_t)j * 8);
            FMA1(cur, f);
            cur = nxt;
        }
        { float f = *(const float*)(fl + (size_t)j * 8); FMA1(cur, f); }
    }
#undef FMA1
    // denominator reduce within 16-lane group
#pragma unroll
    for (int m = 8; m >= 1; m >>= 1) { sl0 += __shfl_xor(sl0, m); sl1 += __shfl_xor(sl1, m); }
    float sum = (ql >= 8) ? sl1 : sl0;
    float rs = __builtin_amdgcn_rcpf(sum);  // ~1 ulp, << fp16 storage error
    int c = 8 * ql;
    half8v o;
#pragma unroll
    for (int i = 0; i < 8; i++) {
        float vv = fmaf(acc[i], rs, b1[c + i]);
        o[i] = (_Float16)(vv > 0.f ? vv : 0.f);   // relu
    }
    *(half8v*)&h[(size_t)n * 128 + c] = o;
}

// -------- Layer 2 GEMM: direct-to-register fp16 fragments, att folded --------

__global__ __launch_bounds__(256) void gemm2_kernel(
        const _Float16* __restrict__ h, const _Float16* __restrict__ W2T,
        _Float16* __restrict__ xw2h, float* __restrict__ as2, float* __restrict__ ad2) {
    __shared__ _Float16 xs[64 * 72];        // output transpose only
    int tid = threadIdx.x;
    int base = blockIdx.x * 64;
    int w = tid >> 6, l = tid & 63;
    int quad = l >> 4, lq = l & 15;
    int row = base + 16 * w + lq;
    size_t rbase = (size_t)(row < N_NODES ? row : 0) * 128;
    half8v a[4];
#pragma unroll
    for (int ks = 0; ks < 4; ks++)
        a[ks] = *(const half8v*)&h[rbase + ks * 32 + quad * 8];
    float4v acc[5];
#pragma unroll
    for (int t = 0; t < 5; t++) acc[t] = (float4v)0.f;
#pragma unroll
    for (int ks = 0; ks < 4; ++ks) {
#pragma unroll
        for (int t = 0; t < 5; t++) {
            half8v b = *(const half8v*)&W2T[(t * 16 + lq) * 128 + ks * 32 + quad * 8];
            acc[t] = __builtin_amdgcn_mfma_f32_16x16x32_f16(a[ks], b, acc[t], 0, 0, 0);
        }
    }
    // attention dots from MFMA tile t=4 (cols 64,65), lanes lq 0..1
    if (lq < 2) {
        float* dst = lq ? ad2 : as2;
#pragma unroll
        for (int r = 0; r < 4; r++) {
            int n = base + 16 * w + quad * 4 + r;
            if (n < N_NODES) dst[n] = acc[4][r];
        }
    }
#pragma unroll
    for (int t = 0; t < 4; t++)
#pragma unroll
        for (int r = 0; r < 4; r++)
            xs[(16 * w + quad * 4 + r) * 72 + t * 16 + lq] = (_Float16)acc[t][r];
    __syncthreads();
    int node = tid >> 2, seg = tid & 3;
    if (base + node < N_NODES) {
#pragma unroll
        for (int i = 0; i < 2; i++) {
            half8v vv = *(const half8v*)&xs[node * 72 + seg * 16 + i * 8];
            *(half8v*)&xw2h[(size_t)(base + node) * 64 + seg * 16 + i * 8] = vv;
        }
    }
}

// ---- Layer 2 aggregation: one node per 8-lane group (8 nodes/wave), fused epilogue ----

__global__ __launch_bounds__(256) void agg2_kernel(
        const int* __restrict__ off, const int* __restrict__ csr_src,
        const float* __restrict__ as2, const float* __restrict__ ad2,
        const _Float16* __restrict__ xw2h, const float* __restrict__ b2,
        const float* __restrict__ lw, float* __restrict__ u, float* __restrict__ v) {
    __shared__ float esm[4][64];            // per-wave f records
    int wv = threadIdx.x >> 6, lane = threadIdx.x & 63;
    int qm = lane & 7;                      // edge lane within group == col-group
    int gb = lane & 56;                     // group base lane
    int n = blockIdx.x * 32 + (wv << 3) + (lane >> 3);   // 32 nodes/block, exact at 3125 blocks
    int s = off[n], e = off[n + 1];
    float adn = ad2[n];
    const float* fl = &esm[wv][gb];
    const _Float16* xq = xw2h + 8 * qm;
    float acc[8];
#pragma unroll
    for (int i = 0; i < 8; i++) acc[i] = 0.f;
    float sl = 0.f;

#define FMA2(R, F) { _Pragma("unroll")                                     \
    for (int i_ = 0; i_ < 8; i_++) acc[i_] = fmaf((float)R[i_], (F), acc[i_]); }

    for (int b = s; b < e; b += 8) {
        int cnt = min(8, e - b);
        int l = qm < cnt ? qm : cnt - 1;
        int srcv = csr_src[b + l];
        float a = as2[srcv];
        float ev = a + adn; ev = ev > 0.f ? ev : NEG_SLOPE * ev;
        float fv = (qm < cnt) ? __expf(ev) : 0.f;
        esm[wv][lane] = fv;
        sl += fv;
        int sj = __shfl(srcv, gb);
        half8v cur = *(const half8v*)&xq[(size_t)sj * 64];
        int j = 0;
        for (; j + 1 < cnt; ++j) {
            int sn = __shfl(srcv, gb + j + 1);
            half8v nxt = *(const half8v*)&xq[(size_t)sn * 64];
            float f = fl[j];
            FMA2(cur, f);
            cur = nxt;
        }
        { float f = fl[j]; FMA2(cur, f); }
    }
#undef FMA2
#pragma unroll
    for (int m = 4; m >= 1; m >>= 1) sl += __shfl_xor(sl, m);
    float rs = __builtin_amdgcn_rcpf(sl);
    int c = 8 * qm;
    float pu = 0.f, pv = 0.f;
#pragma unroll
    for (int i = 0; i < 8; i++) {
        float zi = fmaf(acc[i], rs, b2[c + i]);
        pu = fmaf(zi, lw[c + i], pu);
        pv = fmaf(zi, lw[64 + c + i], pv);
    }
#pragma unroll
    for (int m = 4; m >= 1; m >>= 1) {
        pu += __shfl_xor(pu, m);
        pv += __shfl_xor(pv, m);
    }
    if (qm == 0) { u[n] = pu; v[n] = pv; }
}

// ---------------- Link decode: out = u[s] + v[d] + lb ----------------

__global__ __launch_bounds__(256) void decode_kernel(
        const int* __restrict__ pos_ei, const int* __restrict__ neg_ei,
        const float* __restrict__ u, const float* __restrict__ v,
        const float* __restrict__ lb, float* __restrict__ out) {
    int idx = blockIdx.x * 256 + threadIdx.x;
    if (idx >= 2 * P_CAND) return;
    const int* ei; int p;
    if (idx < P_CAND) { ei = pos_ei; p = idx; }
    else              { ei = neg_ei; p = idx - P_CAND; }
    int sN = ei[p], dN = ei[P_CAND + p];
    out[idx] = u[sN] + v[dN] + lb[0];
}

// ---------------- launch ----------------

extern "C" void kernel_launch(void* const* d_in, const int* in_sizes, int n_in,
                              void* d_out, int out_size, void* d_ws, size_t ws_size,
                              hipStream_t stream) {
    const float* x        = (const float*)d_in[0];
    const int*   ei       = (const int*)d_in[1];
    const int*   pos_ei   = (const int*)d_in[3];
    const int*   neg_ei   = (const int*)d_in[4];
    const float* W1       = (const float*)d_in[5];
    const float* att_src1 = (const float*)d_in[6];
    const float* att_dst1 = (const float*)d_in[7];
    const float* b1       = (const float*)d_in[8];
    const float* W2       = (const float*)d_in[9];
    const float* att_src2 = (const float*)d_in[10];
    const float* att_dst2 = (const float*)d_in[11];
    const float* b2       = (const float*)d_in[12];
    const float* lw       = (const float*)d_in[13];
    const float* lb       = (const float*)d_in[14];
    float* out = (float*)d_out;

    char* ws = (char*)d_ws;
    size_t o = 0;
    auto alloc = [&](size_t bytes) -> char* {
        char* p = ws + o;
        o += (bytes + 511) & ~(size_t)511;
        return p;
    };
    _Float16* xw1h  = (_Float16*)alloc((size_t)N_NODES * 128 * 2);  // reused: xw2h
    _Float16* h     = (_Float16*)alloc((size_t)N_NODES * 128 * 2 + 16384); // +slack for OOB-safe reads
    float*    u     = (float*)alloc((size_t)N_NODES * 4);
    float*    v     = (float*)alloc((size_t)N_NODES * 4);
    float*    as1   = (float*)alloc((size_t)N_NODES * 2 * 4);
    float*    ad1   = (float*)alloc((size_t)N_NODES * 2 * 4);
    float*    as2   = (float*)alloc((size_t)N_NODES * 4);
    float*    ad2   = (float*)alloc((size_t)N_NODES * 4);
    int*      off   = (int*)alloc((size_t)(N_NODES + 1) * 4);
    int*      hist  = (int*)alloc((size_t)NTOT * 4);
    int*      histS = (int*)alloc((size_t)NTOT * 4);
    unsigned* binned= (unsigned*)alloc((size_t)EP * 4);
    int*      csr   = (int*)alloc((size_t)EP * 4);
    _Float16* W1T   = (_Float16*)alloc((size_t)144 * 128 * 2);  // 128 cols + 4 att cols + 12 zero
    _Float16* W2T   = (_Float16*)alloc((size_t)80 * 128 * 2);   // 64 cols + 2 att cols + 14 zero
    _Float16* xw2h  = xw1h;    // xw1h dead after agg1

    prep_kernel<<<112, 256, 0, stream>>>(W1, W2, att_src1, att_dst1, att_src2, att_dst2, W1T, W2T);
    hist_kernel<<<NB2, 256, 0, stream>>>(ei, hist);
    scan2_kernel<<<1, 1024, 0, stream>>>(hist, histS);
    scatterbin_kernel<<<NB2, 256, 0, stream>>>(ei, histS, binned);
    binsort_kernel<<<NBIN, 1024, 0, stream>>>(binned, histS, off, csr);
    gemm1_kernel<<<(N_NODES + 63) / 64, 256, 0, stream>>>(x, W1T, xw1h, as1, ad1);
    agg1_kernel<<<N_NODES / 16, 256, 0, stream>>>(off, csr, as1, ad1, xw1h, b1, h);
    gemm2_kernel<<<(N_NODES + 63) / 64, 256, 0, stream>>>(h, W2T, xw2h, as2, ad2);
    agg2_kernel<<<N_NODES / 32, 256, 0, stream>>>(off, csr, as2, ad2, xw2h, b2, lw, u, v);
    decode_kernel<<<(2 * P_CAND + 255) / 256, 256, 0, stream>>>(pos_ei, neg_ei, u, v, lb, out);
}

// Round 7
// 338.942 us; speedup vs baseline: 1.1140x; 1.0497x over previous
//
#include <hip/hip_runtime.h>

#define N_NODES 100000
#define E_EDGES 1600000
#define EP      (E_EDGES + N_NODES)   // edges + self loops = 1,700,000
#define P_CAND  262144
#define IN_C    128
#define HID     64
#define NEG_SLOPE 0.2f

#define NBIN  196            // ceil(100000/512) bins of 512 nodes
#define NB2   256            // blocks for hist/scatterbin
#define EPB   ((EP + NB2 - 1) / NB2)   // 6641 edges per block
#define NTOT  (NBIN * NB2)   // 50176 (= 1024*49)

typedef _Float16 half4v __attribute__((ext_vector_type(4)));
typedef _Float16 half8v __attribute__((ext_vector_type(8)));
typedef float    float4v __attribute__((ext_vector_type(4)));

// ---------------- CSR build: deterministic 2-level counting sort ----------------

__global__ __launch_bounds__(256) void hist_kernel(const int* __restrict__ ei,
                                                   int* __restrict__ hist) {
    __shared__ int lh[NBIN];
    for (int t = threadIdx.x; t < NBIN; t += 256) lh[t] = 0;
    __syncthreads();
    int start = blockIdx.x * EPB;
    int end = min(start + EPB, EP);
    for (int i = start + threadIdx.x; i < end; i += 256) {
        int dst = (i < E_EDGES) ? ei[E_EDGES + i] : (i - E_EDGES);
        atomicAdd(&lh[dst >> 9], 1);
    }
    __syncthreads();
    for (int t = threadIdx.x; t < NBIN; t += 256) hist[t * NB2 + blockIdx.x] = lh[t];
}

__global__ __launch_bounds__(1024) void scan2_kernel(const int* __restrict__ hist,
                                                     int* __restrict__ histS) {
    __shared__ int s[1024];
    int t = threadIdx.x;
    int b0 = t * 49;                       // 1024*49 == 50176
    int sum = 0;
    for (int i = 0; i < 49; i++) sum += hist[b0 + i];
    s[t] = sum;
    __syncthreads();
    for (int d = 1; d < 1024; d <<= 1) {
        int v = (t >= d) ? s[t - d] : 0;
        __syncthreads();
        s[t] += v;
        __syncthreads();
    }
    int run = s[t] - sum;
    for (int i = 0; i < 49; i++) { int hv = hist[b0 + i]; histS[b0 + i] = run; run += hv; }
}

__global__ __launch_bounds__(256) void scatterbin_kernel(const int* __restrict__ ei,
                                                         const int* __restrict__ histS,
                                                         unsigned* __restrict__ binned) {
    __shared__ int cur[NBIN];
    for (int t = threadIdx.x; t < NBIN; t += 256) cur[t] = histS[t * NB2 + blockIdx.x];
    __syncthreads();
    int start = blockIdx.x * EPB;
    int end = min(start + EPB, EP);
    for (int i = start + threadIdx.x; i < end; i += 256) {
        int src, dst;
        if (i < E_EDGES) { src = ei[i]; dst = ei[E_EDGES + i]; }
        else             { src = i - E_EDGES; dst = src; }
        int pos = atomicAdd(&cur[dst >> 9], 1);
        binned[pos] = (unsigned)src | ((unsigned)(dst & 511) << 17);
    }
}

__global__ __launch_bounds__(1024) void binsort_kernel(const unsigned* __restrict__ binned,
                                                       const int* __restrict__ histS,
                                                       int* __restrict__ off,
                                                       int* __restrict__ csr) {
    __shared__ int lh[512];
    __shared__ int lsc[512];
    int b = blockIdx.x, t = threadIdx.x;
    int base = histS[b * NB2];
    int endv = (b == NBIN - 1) ? EP : histS[(b + 1) * NB2];
    if (t < 512) lh[t] = 0;
    __syncthreads();
    for (int i = base + t; i < endv; i += 1024)
        atomicAdd(&lh[binned[i] >> 17], 1);
    __syncthreads();
    if (t < 512) lsc[t] = lh[t];
    __syncthreads();
    for (int d = 1; d < 512; d <<= 1) {
        int v = (t >= d && t < 512) ? lsc[t - d] : 0;
        __syncthreads();
        if (t < 512) lsc[t] += v;
        __syncthreads();
    }
    if (t < 512) {
        int ex = lsc[t] - lh[t];
        int node = b * 512 + t;
        if (node <= N_NODES) off[node] = base + ex;
        lh[t] = base + ex;
    }
    __syncthreads();
    for (int i = base + t; i < endv; i += 1024) {
        unsigned v = binned[i];
        int pos = atomicAdd(&lh[v >> 17], 1);
        csr[pos] = (int)(v & 0x1FFFFu);
    }
}

// ---- Weight prep: fp16 transposed copies + folded attention columns W·a ----
// W1T layout: [col][k], col 0..143 (128 real, 4 att-dot cols, 12 zero pad)
// W2T layout: [col][k], col 0..79  (64 real, 2 att-dot cols, 14 zero pad)

__global__ __launch_bounds__(256) void prep_kernel(
        const float* __restrict__ W1, const float* __restrict__ W2,
        const float* __restrict__ att_src1, const float* __restrict__ att_dst1,
        const float* __restrict__ att_src2, const float* __restrict__ att_dst2,
        _Float16* __restrict__ W1T, _Float16* __restrict__ W2T) {
    int idx = blockIdx.x * 256 + threadIdx.x;
    if (idx < 16384) {
        int col = idx >> 7, k = idx & 127;
        W1T[idx] = (_Float16)W1[k * 128 + col];
    } else if (idx < 16896) {
        int j = idx - 16384;
        int c4 = j >> 7, k = j & 127;   // c4: 0=as_h0 1=as_h1 2=ad_h0 3=ad_h1
        const float* av = (c4 < 2 ? att_src1 : att_dst1) + (c4 & 1) * 64;
        const float* wr = W1 + k * 128 + (c4 & 1) * 64;
        float s = 0.f;
        for (int c = 0; c < 64; c++) s += wr[c] * av[c];
        W1T[(128 + c4) * 128 + k] = (_Float16)s;
    } else if (idx < 18432) {
        W1T[132 * 128 + (idx - 16896)] = (_Float16)0.f;
    } else if (idx < 26624) {
        int j = idx - 18432;
        int col = j >> 7, k = j & 127;
        W2T[col * 128 + k] = (_Float16)W2[k * 64 + col];
    } else if (idx < 26880) {
        int j = idx - 26624;
        int c2 = j >> 7, k = j & 127;   // 0=as2 1=ad2
        const float* av = c2 ? att_dst2 : att_src2;
        const float* wr = W2 + k * 64;
        float s = 0.f;
        for (int c = 0; c < 64; c++) s += wr[c] * av[c];
        W2T[(64 + c2) * 128 + k] = (_Float16)s;
    } else if (idx < 28672) {
        W2T[66 * 128 + (idx - 26880)] = (_Float16)0.f;
    }
}

// -------- Layer 1 GEMM: direct-to-register fragments, att folded into MFMA --------
// Epilogue: per-row int8 quantization (row-max scale) -> 12.8MB table + 400KB scales.

__global__ __launch_bounds__(256) void gemm1_kernel(
        const float* __restrict__ x, const _Float16* __restrict__ W1T,
        unsigned char* __restrict__ xw1q, float* __restrict__ scl,
        float* __restrict__ as1, float* __restrict__ ad1) {
    __shared__ _Float16 xs[64 * 136];       // output transpose only
    int tid = threadIdx.x;
    int base = blockIdx.x * 64;
    int w = tid >> 6, l = tid & 63;
    int quad = l >> 4, lq = l & 15;
    int row = base + 16 * w + lq;
    size_t rb = (size_t)(row < N_NODES ? row : 0) * 32;   // float4 units
    const float4* x4 = (const float4*)x;
    // A fragments: 8 independent dwordx4 loads, deep MLP
    float4 af[8];
#pragma unroll
    for (int ks = 0; ks < 4; ks++) {
        af[2 * ks]     = x4[rb + ks * 8 + quad * 2];
        af[2 * ks + 1] = x4[rb + ks * 8 + quad * 2 + 1];
    }
    half8v a[4];
#pragma unroll
    for (int ks = 0; ks < 4; ks++) {
        float4 u0 = af[2 * ks], u1 = af[2 * ks + 1];
        half8v t;
        t[0] = (_Float16)u0.x; t[1] = (_Float16)u0.y; t[2] = (_Float16)u0.z; t[3] = (_Float16)u0.w;
        t[4] = (_Float16)u1.x; t[5] = (_Float16)u1.y; t[6] = (_Float16)u1.z; t[7] = (_Float16)u1.w;
        a[ks] = t;
    }
    float4v acc[9];
#pragma unroll
    for (int t = 0; t < 9; t++) acc[t] = (float4v)0.f;
#pragma unroll
    for (int ks = 0; ks < 4; ++ks) {
#pragma unroll
        for (int t = 0; t < 9; t++) {
            half8v b = *(const half8v*)&W1T[(t * 16 + lq) * 128 + ks * 32 + quad * 8];
            acc[t] = __builtin_amdgcn_mfma_f32_16x16x32_f16(a[ks], b, acc[t], 0, 0, 0);
        }
    }
    // attention dots came out of MFMA tile t=8 (cols 128..131), lanes lq 0..3
    if (lq < 4) {
        float* dst = (lq < 2) ? as1 : ad1;
        int hsel = lq & 1;
#pragma unroll
        for (int r = 0; r < 4; r++) {
            int n = base + 16 * w + quad * 4 + r;
            if (n < N_NODES) dst[2 * n + hsel] = acc[8][r];
        }
    }
    // transpose via LDS
#pragma unroll
    for (int t = 0; t < 8; t++)
#pragma unroll
        for (int r = 0; r < 4; r++)
            xs[(16 * w + quad * 4 + r) * 136 + t * 16 + lq] = (_Float16)acc[t][r];
    __syncthreads();
    // int8 row quantization: 4 lanes per node, 32 cols each
    int node = tid >> 2, seg = tid & 3;
    if (base + node < N_NODES) {
        float vals[32];
        float mx = 0.f;
#pragma unroll
        for (int i = 0; i < 4; i++) {
            half8v vv = *(const half8v*)&xs[node * 136 + seg * 32 + i * 8];
#pragma unroll
            for (int k = 0; k < 8; k++) {
                float f = (float)vv[k];
                vals[i * 8 + k] = f;
                mx = fmaxf(mx, fabsf(f));
            }
        }
        mx = fmaxf(mx, __shfl_xor(mx, 1));   // 4 lanes of a node are consecutive
        mx = fmaxf(mx, __shfl_xor(mx, 2));
        mx = fmaxf(mx, 1e-20f);
        float r = 127.f / mx;
        unsigned pk[8];
#pragma unroll
        for (int d = 0; d < 8; d++) {
            unsigned u0 = (unsigned)(__float2int_rn(vals[d * 4 + 0] * r) + 128);
            unsigned u1 = (unsigned)(__float2int_rn(vals[d * 4 + 1] * r) + 128);
            unsigned u2 = (unsigned)(__float2int_rn(vals[d * 4 + 2] * r) + 128);
            unsigned u3 = (unsigned)(__float2int_rn(vals[d * 4 + 3] * r) + 128);
            pk[d] = u0 | (u1 << 8) | (u2 << 16) | (u3 << 24);
        }
        unsigned* dst = (unsigned*)&xw1q[(size_t)(base + node) * 128 + seg * 32];
        *(uint4*)dst       = make_uint4(pk[0], pk[1], pk[2], pk[3]);
        *(uint4*)(dst + 4) = make_uint4(pk[4], pk[5], pk[6], pk[7]);
        if (seg == 0) scl[base + node] = mx * (1.f / 127.f);
    }
}

// ---- Layer 1 aggregation: 16-lane groups, int8 dequant gather (12.8MB table) ----
// sum f*w = sum (f*s)*u - 128*sum(f*s): offset folds into one csum scalar.

__global__ __launch_bounds__(256) void agg1_kernel(
        const int* __restrict__ off, const int* __restrict__ csr_src,
        const float* __restrict__ as1, const float* __restrict__ ad1,
        const unsigned char* __restrict__ xw1q, const float* __restrict__ scl,
        const float* __restrict__ b1, _Float16* __restrict__ h) {
    __shared__ float2 esm[4][64];           // per-wave (f0, f1) records
    int wv = threadIdx.x >> 6, lane = threadIdx.x & 63;
    int ql = lane & 15;                     // edge lane within group == col-group (ql<8: head0)
    int gb = lane & 48;                     // group base lane
    int n = blockIdx.x * 16 + (wv << 2) + (lane >> 4);   // 16 nodes/block, exact at 6250 blocks
    int s = off[n], e = off[n + 1];
    float adn0 = ad1[2 * n], adn1 = ad1[2 * n + 1];
    const char* fl = (const char*)&esm[wv][gb] + ((ql >= 8) ? 4 : 0);
    const unsigned char* xq = xw1q + 8 * ql; // 8 u8 cols per lane
    float acc[8];
#pragma unroll
    for (int i = 0; i < 8; i++) acc[i] = 0.f;
    float sl0 = 0.f, sl1 = 0.f;             // per-lane denominator partials
    float csum = 0.f;                       // sum of g = f*s (per-lane head-specific)

#define DEQ1(QV, G) { \
    acc[0] = fmaf((float)((QV).x & 0xffu), (G), acc[0]); \
    acc[1] = fmaf((float)(((QV).x >> 8) & 0xffu), (G), acc[1]); \
    acc[2] = fmaf((float)(((QV).x >> 16) & 0xffu), (G), acc[2]); \
    acc[3] = fmaf((float)((QV).x >> 24), (G), acc[3]); \
    acc[4] = fmaf((float)((QV).y & 0xffu), (G), acc[4]); \
    acc[5] = fmaf((float)(((QV).y >> 8) & 0xffu), (G), acc[5]); \
    acc[6] = fmaf((float)(((QV).y >> 16) & 0xffu), (G), acc[6]); \
    acc[7] = fmaf((float)((QV).y >> 24), (G), acc[7]); }

    for (int b = s; b < e; b += 16) {
        int cnt = min(16, e - b);
        int l = ql < cnt ? ql : cnt - 1;
        int srcv = csr_src[b + l];
        float2 a = *(const float2*)&as1[2 * srcv];
        float e0 = a.x + adn0; e0 = e0 > 0.f ? e0 : NEG_SLOPE * e0;
        float e1 = a.y + adn1; e1 = e1 > 0.f ? e1 : NEG_SLOPE * e1;
        float f0v = (ql < cnt) ? __expf(e0) : 0.f;
        float f1v = (ql < cnt) ? __expf(e1) : 0.f;
        esm[wv][lane] = make_float2(f0v, f1v);
        sl0 += f0v; sl1 += f1v;
        // 2-deep rotation over this chunk's edges (group-uniform trip count)
        int sj = __shfl(srcv, gb);
        uint2 qcur = *(const uint2*)&xq[(size_t)sj * 128];
        float scur = scl[sj];
        int j = 0;
        for (; j + 1 < cnt; ++j) {
            int sn = __shfl(srcv, gb + j + 1);
            uint2 qnxt = *(const uint2*)&xq[(size_t)sn * 128];
            float snxt = scl[sn];
            float f = *(const float*)(fl + (size_t)j * 8);
            float g = f * scur;
            csum += g;
            DEQ1(qcur, g)
            qcur = qnxt; scur = snxt;
        }
        { float f = *(const float*)(fl + (size_t)j * 8);
          float g = f * scur; csum += g; DEQ1(qcur, g) }
    }
#undef DEQ1
    // denominator reduce within 16-lane group
#pragma unroll
    for (int m = 8; m >= 1; m >>= 1) { sl0 += __shfl_xor(sl0, m); sl1 += __shfl_xor(sl1, m); }
    float sum = (ql >= 8) ? sl1 : sl0;
    float rs = __builtin_amdgcn_rcpf(sum);  // ~1 ulp, << storage quant error
    float base8 = -128.f * csum;
    int c = 8 * ql;
    half8v o;
#pragma unroll
    for (int i = 0; i < 8; i++) {
        float vv = fmaf(acc[i] + base8, rs, b1[c + i]);
        o[i] = (_Float16)(vv > 0.f ? vv : 0.f);   // relu
    }
    *(half8v*)&h[(size_t)n * 128 + c] = o;
}

// -------- Layer 2 GEMM: direct-to-register fp16 fragments, att folded --------

__global__ __launch_bounds__(256) void gemm2_kernel(
        const _Float16* __restrict__ h, const _Float16* __restrict__ W2T,
        _Float16* __restrict__ xw2h, float* __restrict__ as2, float* __restrict__ ad2) {
    __shared__ _Float16 xs[64 * 72];        // output transpose only
    int tid = threadIdx.x;
    int base = blockIdx.x * 64;
    int w = tid >> 6, l = tid & 63;
    int quad = l >> 4, lq = l & 15;
    int row = base + 16 * w + lq;
    size_t rbase = (size_t)(row < N_NODES ? row : 0) * 128;
    half8v a[4];
#pragma unroll
    for (int ks = 0; ks < 4; ks++)
        a[ks] = *(const half8v*)&h[rbase + ks * 32 + quad * 8];
    float4v acc[5];
#pragma unroll
    for (int t = 0; t < 5; t++) acc[t] = (float4v)0.f;
#pragma unroll
    for (int ks = 0; ks < 4; ++ks) {
#pragma unroll
        for (int t = 0; t < 5; t++) {
            half8v b = *(const half8v*)&W2T[(t * 16 + lq) * 128 + ks * 32 + quad * 8];
            acc[t] = __builtin_amdgcn_mfma_f32_16x16x32_f16(a[ks], b, acc[t], 0, 0, 0);
        }
    }
    // attention dots from MFMA tile t=4 (cols 64,65), lanes lq 0..1
    if (lq < 2) {
        float* dst = lq ? ad2 : as2;
#pragma unroll
        for (int r = 0; r < 4; r++) {
            int n = base + 16 * w + quad * 4 + r;
            if (n < N_NODES) dst[n] = acc[4][r];
        }
    }
#pragma unroll
    for (int t = 0; t < 4; t++)
#pragma unroll
        for (int r = 0; r < 4; r++)
            xs[(16 * w + quad * 4 + r) * 72 + t * 16 + lq] = (_Float16)acc[t][r];
    __syncthreads();
    int node = tid >> 2, seg = tid & 3;
    if (base + node < N_NODES) {
#pragma unroll
        for (int i = 0; i < 2; i++) {
            half8v vv = *(const half8v*)&xs[node * 72 + seg * 16 + i * 8];
            *(half8v*)&xw2h[(size_t)(base + node) * 64 + seg * 16 + i * 8] = vv;
        }
    }
}

// ---- Layer 2 aggregation: one node per 8-lane group (8 nodes/wave), fused epilogue ----

__global__ __launch_bounds__(256) void agg2_kernel(
        const int* __restrict__ off, const int* __restrict__ csr_src,
        const float* __restrict__ as2, const float* __restrict__ ad2,
        const _Float16* __restrict__ xw2h, const float* __restrict__ b2,
        const float* __restrict__ lw, float* __restrict__ u, float* __restrict__ v) {
    __shared__ float esm[4][64];            // per-wave f records
    int wv = threadIdx.x >> 6, lane = threadIdx.x & 63;
    int qm = lane & 7;                      // edge lane within group == col-group
    int gb = lane & 56;                     // group base lane
    int n = blockIdx.x * 32 + (wv << 3) + (lane >> 3);   // 32 nodes/block, exact at 3125 blocks
    int s = off[n], e = off[n + 1];
    float adn = ad2[n];
    const float* fl = &esm[wv][gb];
    const _Float16* xq = xw2h + 8 * qm;
    float acc[8];
#pragma unroll
    for (int i = 0; i < 8; i++) acc[i] = 0.f;
    float sl = 0.f;

#define FMA2(R, F) { _Pragma("unroll")                                     \
    for (int i_ = 0; i_ < 8; i_++) acc[i_] = fmaf((float)R[i_], (F), acc[i_]); }

    for (int b = s; b < e; b += 8) {
        int cnt = min(8, e - b);
        int l = qm < cnt ? qm : cnt - 1;
        int srcv = csr_src[b + l];
        float a = as2[srcv];
        float ev = a + adn; ev = ev > 0.f ? ev : NEG_SLOPE * ev;
        float fv = (qm < cnt) ? __expf(ev) : 0.f;
        esm[wv][lane] = fv;
        sl += fv;
        int sj = __shfl(srcv, gb);
        half8v cur = *(const half8v*)&xq[(size_t)sj * 64];
        int j = 0;
        for (; j + 1 < cnt; ++j) {
            int sn = __shfl(srcv, gb + j + 1);
            half8v nxt = *(const half8v*)&xq[(size_t)sn * 64];
            float f = fl[j];
            FMA2(cur, f);
            cur = nxt;
        }
        { float f = fl[j]; FMA2(cur, f); }
    }
#undef FMA2
#pragma unroll
    for (int m = 4; m >= 1; m >>= 1) sl += __shfl_xor(sl, m);
    float rs = __builtin_amdgcn_rcpf(sl);
    int c = 8 * qm;
    float pu = 0.f, pv = 0.f;
#pragma unroll
    for (int i = 0; i < 8; i++) {
        float zi = fmaf(acc[i], rs, b2[c + i]);
        pu = fmaf(zi, lw[c + i], pu);
        pv = fmaf(zi, lw[64 + c + i], pv);
    }
#pragma unroll
    for (int m = 4; m >= 1; m >>= 1) {
        pu += __shfl_xor(pu, m);
        pv += __shfl_xor(pv, m);
    }
    if (qm == 0) { u[n] = pu; v[n] = pv; }
}

// ---------------- Link decode: out = u[s] + v[d] + lb ----------------

__global__ __launch_bounds__(256) void decode_kernel(
        const int* __restrict__ pos_ei, const int* __restrict__ neg_ei,
        const float* __restrict__ u, const float* __restrict__ v,
        const float* __restrict__ lb, float* __restrict__ out) {
    int idx = blockIdx.x * 256 + threadIdx.x;
    if (idx >= 2 * P_CAND) return;
    const int* ei; int p;
    if (idx < P_CAND) { ei = pos_ei; p = idx; }
    else              { ei = neg_ei; p = idx - P_CAND; }
    int sN = ei[p], dN = ei[P_CAND + p];
    out[idx] = u[sN] + v[dN] + lb[0];
}

// ---------------- launch ----------------

extern "C" void kernel_launch(void* const* d_in, const int* in_sizes, int n_in,
                              void* d_out, int out_size, void* d_ws, size_t ws_size,
                              hipStream_t stream) {
    const float* x        = (const float*)d_in[0];
    const int*   ei       = (const int*)d_in[1];
    const int*   pos_ei   = (const int*)d_in[3];
    const int*   neg_ei   = (const int*)d_in[4];
    const float* W1       = (const float*)d_in[5];
    const float* att_src1 = (const float*)d_in[6];
    const float* att_dst1 = (const float*)d_in[7];
    const float* b1       = (const float*)d_in[8];
    const float* W2       = (const float*)d_in[9];
    const float* att_src2 = (const float*)d_in[10];
    const float* att_dst2 = (const float*)d_in[11];
    const float* b2       = (const float*)d_in[12];
    const float* lw       = (const float*)d_in[13];
    const float* lb       = (const float*)d_in[14];
    float* out = (float*)d_out;

    char* ws = (char*)d_ws;
    size_t o = 0;
    auto alloc = [&](size_t bytes) -> char* {
        char* p = ws + o;
        o += (bytes + 511) & ~(size_t)511;
        return p;
    };
    unsigned char* xw1q = (unsigned char*)alloc((size_t)N_NODES * 128);   // int8 table; reused: xw2h
    float*    scl   = (float*)alloc((size_t)N_NODES * 4);
    _Float16* h     = (_Float16*)alloc((size_t)N_NODES * 128 * 2 + 16384); // +slack for OOB-safe reads
    float*    u     = (float*)alloc((size_t)N_NODES * 4);
    float*    v     = (float*)alloc((size_t)N_NODES * 4);
    float*    as1   = (float*)alloc((size_t)N_NODES * 2 * 4);
    float*    ad1   = (float*)alloc((size_t)N_NODES * 2 * 4);
    float*    as2   = (float*)alloc((size_t)N_NODES * 4);
    float*    ad2   = (float*)alloc((size_t)N_NODES * 4);
    int*      off   = (int*)alloc((size_t)(N_NODES + 1) * 4);
    int*      hist  = (int*)alloc((size_t)NTOT * 4);
    int*      histS = (int*)alloc((size_t)NTOT * 4);
    unsigned* binned= (unsigned*)alloc((size_t)EP * 4);
    int*      csr   = (int*)alloc((size_t)EP * 4);
    _Float16* W1T   = (_Float16*)alloc((size_t)144 * 128 * 2);  // 128 cols + 4 att cols + 12 zero
    _Float16* W2T   = (_Float16*)alloc((size_t)80 * 128 * 2);   // 64 cols + 2 att cols + 14 zero
    _Float16* xw2h  = (_Float16*)xw1q;   // xw1q (12.8MB) dead after agg1; xw2h needs 12.8MB

    prep_kernel<<<112, 256, 0, stream>>>(W1, W2, att_src1, att_dst1, att_src2, att_dst2, W1T, W2T);
    hist_kernel<<<NB2, 256, 0, stream>>>(ei, hist);
    scan2_kernel<<<1, 1024, 0, stream>>>(hist, histS);
    scatterbin_kernel<<<NB2, 256, 0, stream>>>(ei, histS, binned);
    binsort_kernel<<<NBIN, 1024, 0, stream>>>(binned, histS, off, csr);
    gemm1_kernel<<<(N_NODES + 63) / 64, 256, 0, stream>>>(x, W1T, xw1q, scl, as1, ad1);
    agg1_kernel<<<N_NODES / 16, 256, 0, stream>>>(off, csr, as1, ad1, xw1q, scl, b1, h);
    gemm2_kernel<<<(N_NODES + 63) / 64, 256, 0, stream>>>(h, W2T, xw2h, as2, ad2);
    agg2_kernel<<<N_NODES / 32, 256, 0, stream>>>(off, csr, as2, ad2, xw2h, b2, lw, u, v);
    decode_kernel<<<(2 * P_CAND + 255) / 256, 256, 0, stream>>>(pos_ei, neg_ei, u, v, lb, out);
}

// Round 8
// 289.130 us; speedup vs baseline: 1.3059x; 1.1723x over previous
//
#include <hip/hip_runtime.h>

#define N_NODES 100000
#define E_EDGES 1600000
#define EP      (E_EDGES + N_NODES)   // edges + self loops = 1,700,000
#define P_CAND  262144
#define IN_C    128
#define HID     64
#define NEG_SLOPE 0.2f

#define NBIN  196            // ceil(100000/512) bins of 512 nodes
#define NB2   256            // blocks for hist/scatterbin
#define EPB   ((EP + NB2 - 1) / NB2)   // 6641 edges per block
#define NTOT  (NBIN * NB2)   // 50176 (= 1024*49)

typedef _Float16 half4v __attribute__((ext_vector_type(4)));
typedef _Float16 half8v __attribute__((ext_vector_type(8)));
typedef float    float4v __attribute__((ext_vector_type(4)));

// ---------------- CSR build: deterministic 2-level counting sort ----------------

__global__ __launch_bounds__(256) void hist_kernel(const int* __restrict__ ei,
                                                   int* __restrict__ hist) {
    __shared__ int lh[NBIN];
    for (int t = threadIdx.x; t < NBIN; t += 256) lh[t] = 0;
    __syncthreads();
    int start = blockIdx.x * EPB;
    int end = min(start + EPB, EP);
    for (int i = start + threadIdx.x; i < end; i += 256) {
        int dst = (i < E_EDGES) ? ei[E_EDGES + i] : (i - E_EDGES);
        atomicAdd(&lh[dst >> 9], 1);
    }
    __syncthreads();
    for (int t = threadIdx.x; t < NBIN; t += 256) hist[t * NB2 + blockIdx.x] = lh[t];
}

__global__ __launch_bounds__(1024) void scan2_kernel(const int* __restrict__ hist,
                                                     int* __restrict__ histS) {
    __shared__ int s[1024];
    int t = threadIdx.x;
    int b0 = t * 49;                       // 1024*49 == 50176
    int sum = 0;
    for (int i = 0; i < 49; i++) sum += hist[b0 + i];
    s[t] = sum;
    __syncthreads();
    for (int d = 1; d < 1024; d <<= 1) {
        int v = (t >= d) ? s[t - d] : 0;
        __syncthreads();
        s[t] += v;
        __syncthreads();
    }
    int run = s[t] - sum;
    for (int i = 0; i < 49; i++) { int hv = hist[b0 + i]; histS[b0 + i] = run; run += hv; }
}

__global__ __launch_bounds__(256) void scatterbin_kernel(const int* __restrict__ ei,
                                                         const int* __restrict__ histS,
                                                         unsigned* __restrict__ binned) {
    __shared__ int cur[NBIN];
    for (int t = threadIdx.x; t < NBIN; t += 256) cur[t] = histS[t * NB2 + blockIdx.x];
    __syncthreads();
    int start = blockIdx.x * EPB;
    int end = min(start + EPB, EP);
    for (int i = start + threadIdx.x; i < end; i += 256) {
        int src, dst;
        if (i < E_EDGES) { src = ei[i]; dst = ei[E_EDGES + i]; }
        else             { src = i - E_EDGES; dst = src; }
        int pos = atomicAdd(&cur[dst >> 9], 1);
        binned[pos] = (unsigned)src | ((unsigned)(dst & 511) << 17);
    }
}

__global__ __launch_bounds__(1024) void binsort_kernel(const unsigned* __restrict__ binned,
                                                       const int* __restrict__ histS,
                                                       int* __restrict__ off,
                                                       int* __restrict__ csr) {
    __shared__ int lh[512];
    __shared__ int lsc[512];
    int b = blockIdx.x, t = threadIdx.x;
    int base = histS[b * NB2];
    int endv = (b == NBIN - 1) ? EP : histS[(b + 1) * NB2];
    if (t < 512) lh[t] = 0;
    __syncthreads();
    for (int i = base + t; i < endv; i += 1024)
        atomicAdd(&lh[binned[i] >> 17], 1);
    __syncthreads();
    if (t < 512) lsc[t] = lh[t];
    __syncthreads();
    for (int d = 1; d < 512; d <<= 1) {
        int v = (t >= d && t < 512) ? lsc[t - d] : 0;
        __syncthreads();
        if (t < 512) lsc[t] += v;
        __syncthreads();
    }
    if (t < 512) {
        int ex = lsc[t] - lh[t];
        int node = b * 512 + t;
        if (node <= N_NODES) off[node] = base + ex;
        lh[t] = base + ex;
    }
    __syncthreads();
    for (int i = base + t; i < endv; i += 1024) {
        unsigned v = binned[i];
        int pos = atomicAdd(&lh[v >> 17], 1);
        csr[pos] = (int)(v & 0x1FFFFu);
    }
}

// ---- Weight prep ----
// W1T: [col][k], col 0..143 (128 real, 4 att-dot cols, 12 zero pad)
// W2T: [col][k], col 0..15: 0=W2·a_src2 1=W2·a_dst2 2=W2·lw1 3=W2·lw2, 4..15 zero
// cvec: (b2·lw1, b2·lw2)

__global__ __launch_bounds__(256) void prep_kernel(
        const float* __restrict__ W1, const float* __restrict__ W2,
        const float* __restrict__ att_src1, const float* __restrict__ att_dst1,
        const float* __restrict__ att_src2, const float* __restrict__ att_dst2,
        const float* __restrict__ b2, const float* __restrict__ lw,
        _Float16* __restrict__ W1T, _Float16* __restrict__ W2T,
        float* __restrict__ cvec) {
    int idx = blockIdx.x * 256 + threadIdx.x;
    if (idx < 16384) {
        int col = idx >> 7, k = idx & 127;
        W1T[idx] = (_Float16)W1[k * 128 + col];
    } else if (idx < 16896) {
        int j = idx - 16384;
        int c4 = j >> 7, k = j & 127;   // c4: 0=as_h0 1=as_h1 2=ad_h0 3=ad_h1
        const float* av = (c4 < 2 ? att_src1 : att_dst1) + (c4 & 1) * 64;
        const float* wr = W1 + k * 128 + (c4 & 1) * 64;
        float s = 0.f;
        for (int c = 0; c < 64; c++) s += wr[c] * av[c];
        W1T[(128 + c4) * 128 + k] = (_Float16)s;
    } else if (idx < 18432) {
        W1T[132 * 128 + (idx - 16896)] = (_Float16)0.f;
    } else if (idx < 18944) {
        int j = idx - 18432;
        int c4 = j >> 7, k = j & 127;   // 0=as2 1=ad2 2=p1 3=p2
        const float* av = (c4 == 0) ? att_src2 : (c4 == 1) ? att_dst2
                        : (c4 == 2) ? lw : (lw + 64);
        const float* wr = W2 + k * 64;
        float s = 0.f;
        for (int c = 0; c < 64; c++) s += wr[c] * av[c];
        W2T[c4 * 128 + k] = (_Float16)s;
    } else if (idx < 20480) {
        W2T[512 + (idx - 18944)] = (_Float16)0.f;   // cols 4..15 zero
    } else if (idx < 20482) {
        int c = idx - 20480;                         // 0: b2·lw1, 1: b2·lw2
        const float* lwp = lw + c * 64;
        float s = 0.f;
        for (int i = 0; i < 64; i++) s += b2[i] * lwp[i];
        cvec[c] = s;
    }
}

// -------- Layer 1 GEMM: direct-to-register fragments, att folded into MFMA --------
// Epilogue: per-row int8 quantization; packs (as_h0, as_h1, scale) into asp1 float4.

__global__ __launch_bounds__(256) void gemm1_kernel(
        const float* __restrict__ x, const _Float16* __restrict__ W1T,
        unsigned char* __restrict__ xw1q, float* __restrict__ asp1,
        float* __restrict__ ad1) {
    __shared__ _Float16 xs[64 * 136];       // output transpose only
    int tid = threadIdx.x;
    int base = blockIdx.x * 64;
    int w = tid >> 6, l = tid & 63;
    int quad = l >> 4, lq = l & 15;
    int row = base + 16 * w + lq;
    size_t rb = (size_t)(row < N_NODES ? row : 0) * 32;   // float4 units
    const float4* x4 = (const float4*)x;
    float4 af[8];
#pragma unroll
    for (int ks = 0; ks < 4; ks++) {
        af[2 * ks]     = x4[rb + ks * 8 + quad * 2];
        af[2 * ks + 1] = x4[rb + ks * 8 + quad * 2 + 1];
    }
    half8v a[4];
#pragma unroll
    for (int ks = 0; ks < 4; ks++) {
        float4 u0 = af[2 * ks], u1 = af[2 * ks + 1];
        half8v t;
        t[0] = (_Float16)u0.x; t[1] = (_Float16)u0.y; t[2] = (_Float16)u0.z; t[3] = (_Float16)u0.w;
        t[4] = (_Float16)u1.x; t[5] = (_Float16)u1.y; t[6] = (_Float16)u1.z; t[7] = (_Float16)u1.w;
        a[ks] = t;
    }
    float4v acc[9];
#pragma unroll
    for (int t = 0; t < 9; t++) acc[t] = (float4v)0.f;
#pragma unroll
    for (int ks = 0; ks < 4; ++ks) {
#pragma unroll
        for (int t = 0; t < 9; t++) {
            half8v b = *(const half8v*)&W1T[(t * 16 + lq) * 128 + ks * 32 + quad * 8];
            acc[t] = __builtin_amdgcn_mfma_f32_16x16x32_f16(a[ks], b, acc[t], 0, 0, 0);
        }
    }
    // attention dots from MFMA tile t=8 (cols 128..131), lanes lq 0..3
    if (lq < 4) {
#pragma unroll
        for (int r = 0; r < 4; r++) {
            int n = base + 16 * w + quad * 4 + r;
            if (n < N_NODES) {
                if (lq < 2) asp1[4 * n + lq] = acc[8][r];          // as_h0, as_h1
                else        ad1[2 * n + (lq & 1)] = acc[8][r];     // ad_h0, ad_h1
            }
        }
    }
    // transpose via LDS
#pragma unroll
    for (int t = 0; t < 8; t++)
#pragma unroll
        for (int r = 0; r < 4; r++)
            xs[(16 * w + quad * 4 + r) * 136 + t * 16 + lq] = (_Float16)acc[t][r];
    __syncthreads();
    // int8 row quantization: 4 lanes per node, 32 cols each
    int node = tid >> 2, seg = tid & 3;
    if (base + node < N_NODES) {
        float vals[32];
        float mx = 0.f;
#pragma unroll
        for (int i = 0; i < 4; i++) {
            half8v vv = *(const half8v*)&xs[node * 136 + seg * 32 + i * 8];
#pragma unroll
            for (int k = 0; k < 8; k++) {
                float f = (float)vv[k];
                vals[i * 8 + k] = f;
                mx = fmaxf(mx, fabsf(f));
            }
        }
        mx = fmaxf(mx, __shfl_xor(mx, 1));   // 4 lanes of a node are consecutive
        mx = fmaxf(mx, __shfl_xor(mx, 2));
        mx = fmaxf(mx, 1e-20f);
        float r = 127.f / mx;
        unsigned pk[8];
#pragma unroll
        for (int d = 0; d < 8; d++) {
            unsigned u0 = (unsigned)(__float2int_rn(vals[d * 4 + 0] * r) + 128);
            unsigned u1 = (unsigned)(__float2int_rn(vals[d * 4 + 1] * r) + 128);
            unsigned u2 = (unsigned)(__float2int_rn(vals[d * 4 + 2] * r) + 128);
            unsigned u3 = (unsigned)(__float2int_rn(vals[d * 4 + 3] * r) + 128);
            pk[d] = u0 | (u1 << 8) | (u2 << 16) | (u3 << 24);
        }
        unsigned* dst = (unsigned*)&xw1q[(size_t)(base + node) * 128 + seg * 32];
        *(uint4*)dst       = make_uint4(pk[0], pk[1], pk[2], pk[3]);
        *(uint4*)(dst + 4) = make_uint4(pk[4], pk[5], pk[6], pk[7]);
        if (seg == 0) asp1[4 * (base + node) + 2] = mx * (1.f / 127.f);
    }
}

// ---- Layer 1 aggregation: 16-lane groups, int8 dequant, pre-scaled LDS records ----
// sum f*w = sum g*u - 128*sum g  where g = f*scale (pre-folded in esm).

__global__ __launch_bounds__(256) void agg1_kernel(
        const int* __restrict__ off, const int* __restrict__ csr_src,
        const float* __restrict__ asp1, const float* __restrict__ ad1,
        const unsigned char* __restrict__ xw1q, const float* __restrict__ b1,
        _Float16* __restrict__ h) {
    __shared__ float2 esm[4][64];           // per-wave (g0, g1) records
    int wv = threadIdx.x >> 6, lane = threadIdx.x & 63;
    int ql = lane & 15;                     // edge lane within group == col-group (ql<8: head0)
    int gb = lane & 48;                     // group base lane
    int n = blockIdx.x * 16 + (wv << 2) + (lane >> 4);   // 16 nodes/block, exact at 6250 blocks
    int s = off[n], e = off[n + 1];
    float2 ad = *(const float2*)&ad1[2 * n];
    float adn0 = ad.x, adn1 = ad.y;
    const char* fl = (const char*)&esm[wv][gb] + ((ql >= 8) ? 4 : 0);
    const unsigned char* xq = xw1q + 8 * ql; // 8 u8 cols per lane
    float acc[8];
#pragma unroll
    for (int i = 0; i < 8; i++) acc[i] = 0.f;
    float sl0 = 0.f, sl1 = 0.f;             // per-lane denominator partials
    float csum = 0.f;                       // sum of g (per-lane head-specific)

#define DEQ1(QV, G) { \
    acc[0] = fmaf((float)((QV).x & 0xffu), (G), acc[0]); \
    acc[1] = fmaf((float)(((QV).x >> 8) & 0xffu), (G), acc[1]); \
    acc[2] = fmaf((float)(((QV).x >> 16) & 0xffu), (G), acc[2]); \
    acc[3] = fmaf((float)((QV).x >> 24), (G), acc[3]); \
    acc[4] = fmaf((float)((QV).y & 0xffu), (G), acc[4]); \
    acc[5] = fmaf((float)(((QV).y >> 8) & 0xffu), (G), acc[5]); \
    acc[6] = fmaf((float)(((QV).y >> 16) & 0xffu), (G), acc[6]); \
    acc[7] = fmaf((float)((QV).y >> 24), (G), acc[7]); }

    for (int b = s; b < e; b += 16) {
        int cnt = min(16, e - b);
        int l = ql < cnt ? ql : cnt - 1;
        int srcv = csr_src[b + l];
        float4 ap = *(const float4*)&asp1[4 * srcv];   // (as0, as1, scl, -) one 16B load
        float e0 = ap.x + adn0; e0 = e0 > 0.f ? e0 : NEG_SLOPE * e0;
        float e1 = ap.y + adn1; e1 = e1 > 0.f ? e1 : NEG_SLOPE * e1;
        float f0v = (ql < cnt) ? __expf(e0) : 0.f;
        float f1v = (ql < cnt) ? __expf(e1) : 0.f;
        sl0 += f0v; sl1 += f1v;
        esm[wv][lane] = make_float2(f0v * ap.z, f1v * ap.z);   // pre-scaled
        // 2-deep rotation over this chunk's edges (group-uniform trip count)
        int sj = __shfl(srcv, gb);
        uint2 qcur = *(const uint2*)&xq[(size_t)sj * 128];
        int j = 0;
        for (; j + 1 < cnt; ++j) {
            int sn = __shfl(srcv, gb + j + 1);
            uint2 qnxt = *(const uint2*)&xq[(size_t)sn * 128];
            float g = *(const float*)(fl + (size_t)j * 8);
            csum += g;
            DEQ1(qcur, g)
            qcur = qnxt;
        }
        { float g = *(const float*)(fl + (size_t)j * 8);
          csum += g; DEQ1(qcur, g) }
    }
#undef DEQ1
    // denominator reduce within 16-lane group
#pragma unroll
    for (int m = 8; m >= 1; m >>= 1) { sl0 += __shfl_xor(sl0, m); sl1 += __shfl_xor(sl1, m); }
    float sum = (ql >= 8) ? sl1 : sl0;
    float rs = __builtin_amdgcn_rcpf(sum);  // ~1 ulp, << storage quant error
    float base8 = -128.f * csum;
    int c = 8 * ql;
    half8v o;
#pragma unroll
    for (int i = 0; i < 8; i++) {
        float vv = fmaf(acc[i] + base8, rs, b1[c + i]);
        o[i] = (_Float16)(vv > 0.f ? vv : 0.f);   // relu
    }
    *(half8v*)&h[(size_t)n * 128 + c] = o;
}

// -------- Layer 2 GEMM: single 4-col MFMA tile -> asp2 = (as2, p1, p2, ad2) --------
// p1 = h·(W2·lw1), p2 = h·(W2·lw2): decode projection folded through the GEMM.

__global__ __launch_bounds__(256) void gemm2_kernel(
        const _Float16* __restrict__ h, const _Float16* __restrict__ W2T,
        float* __restrict__ asp2) {
    int tid = threadIdx.x;
    int base = blockIdx.x * 64;
    int w = tid >> 6, l = tid & 63;
    int quad = l >> 4, lq = l & 15;
    int row = base + 16 * w + lq;
    size_t rbase = (size_t)(row < N_NODES ? row : 0) * 128;
    half8v a[4];
#pragma unroll
    for (int ks = 0; ks < 4; ks++)
        a[ks] = *(const half8v*)&h[rbase + ks * 32 + quad * 8];
    float4v acc = (float4v)0.f;
#pragma unroll
    for (int ks = 0; ks < 4; ++ks) {
        half8v b = *(const half8v*)&W2T[lq * 128 + ks * 32 + quad * 8];
        acc = __builtin_amdgcn_mfma_f32_16x16x32_f16(a[ks], b, acc, 0, 0, 0);
    }
    // cols: lq0=as2 lq1=ad2 lq2=p1 lq3=p2 -> asp2 slots (.x=as2,.y=p1,.z=p2,.w=ad2)
    if (lq < 4) {
        int slot = (lq == 0) ? 0 : (lq == 1) ? 3 : (lq == 2) ? 1 : 2;
#pragma unroll
        for (int r = 0; r < 4; r++) {
            int n = base + 16 * w + quad * 4 + r;
            if (n < N_NODES) asp2[4 * n + slot] = acc[r];
        }
    }
}

// ---- Layer 2 aggregation: scalar-only gather (16B/edge, L2-resident table) ----
// u[n] = sum f*p1 / sum f + b2·lw1 ; v[n] = sum f*p2 / sum f + b2·lw2

__global__ __launch_bounds__(256) void agg2_kernel(
        const int* __restrict__ off, const int* __restrict__ csr_src,
        const float* __restrict__ asp2, const float* __restrict__ cvec,
        float* __restrict__ u, float* __restrict__ v) {
    int wv = threadIdx.x >> 6, lane = threadIdx.x & 63;
    int ql = lane & 15;
    int n = blockIdx.x * 16 + (wv << 2) + (lane >> 4);   // 16 nodes/block, exact at 6250 blocks
    int s = off[n], e = off[n + 1];
    float adn = asp2[4 * n + 3];            // ad2 of dst node
    float sf = 0.f, s1 = 0.f, s2 = 0.f;
    for (int j = s + ql; j < e; j += 16) {
        int srcv = csr_src[j];
        float4 ap = *(const float4*)&asp2[4 * srcv];
        float ev = ap.x + adn; ev = ev > 0.f ? ev : NEG_SLOPE * ev;
        float f = __expf(ev);
        sf += f;
        s1 = fmaf(f, ap.y, s1);
        s2 = fmaf(f, ap.z, s2);
    }
#pragma unroll
    for (int m = 8; m >= 1; m >>= 1) {
        sf += __shfl_xor(sf, m);
        s1 += __shfl_xor(s1, m);
        s2 += __shfl_xor(s2, m);
    }
    if (ql == 0) {
        float rs = __builtin_amdgcn_rcpf(sf);
        u[n] = fmaf(s1, rs, cvec[0]);
        v[n] = fmaf(s2, rs, cvec[1]);
    }
}

// ---------------- Link decode: out = u[s] + v[d] + lb ----------------

__global__ __launch_bounds__(256) void decode_kernel(
        const int* __restrict__ pos_ei, const int* __restrict__ neg_ei,
        const float* __restrict__ u, const float* __restrict__ v,
        const float* __restrict__ lb, float* __restrict__ out) {
    int idx = blockIdx.x * 256 + threadIdx.x;
    if (idx >= 2 * P_CAND) return;
    const int* ei; int p;
    if (idx < P_CAND) { ei = pos_ei; p = idx; }
    else              { ei = neg_ei; p = idx - P_CAND; }
    int sN = ei[p], dN = ei[P_CAND + p];
    out[idx] = u[sN] + v[dN] + lb[0];
}

// ---------------- launch ----------------

extern "C" void kernel_launch(void* const* d_in, const int* in_sizes, int n_in,
                              void* d_out, int out_size, void* d_ws, size_t ws_size,
                              hipStream_t stream) {
    const float* x        = (const float*)d_in[0];
    const int*   ei       = (const int*)d_in[1];
    const int*   pos_ei   = (const int*)d_in[3];
    const int*   neg_ei   = (const int*)d_in[4];
    const float* W1       = (const float*)d_in[5];
    const float* att_src1 = (const float*)d_in[6];
    const float* att_dst1 = (const float*)d_in[7];
    const float* b1       = (const float*)d_in[8];
    const float* W2       = (const float*)d_in[9];
    const float* att_src2 = (const float*)d_in[10];
    const float* att_dst2 = (const float*)d_in[11];
    const float* b2       = (const float*)d_in[12];
    const float* lw       = (const float*)d_in[13];
    const float* lb       = (const float*)d_in[14];
    float* out = (float*)d_out;

    char* ws = (char*)d_ws;
    size_t o = 0;
    auto alloc = [&](size_t bytes) -> char* {
        char* p = ws + o;
        o += (bytes + 511) & ~(size_t)511;
        return p;
    };
    unsigned char* xw1q = (unsigned char*)alloc((size_t)N_NODES * 128);   // int8 table
    float*    asp1  = (float*)alloc((size_t)N_NODES * 4 * 4);   // (as0, as1, scl, -)
    float*    ad1   = (float*)alloc((size_t)N_NODES * 2 * 4);
    _Float16* h     = (_Float16*)alloc((size_t)N_NODES * 128 * 2 + 16384); // +slack for OOB-safe reads
    float*    asp2  = (float*)alloc((size_t)N_NODES * 4 * 4);   // (as2, p1, p2, ad2)
    float*    cvec  = (float*)alloc(512);
    float*    u     = (float*)alloc((size_t)N_NODES * 4);
    float*    v     = (float*)alloc((size_t)N_NODES * 4);
    int*      off   = (int*)alloc((size_t)(N_NODES + 1) * 4);
    int*      hist  = (int*)alloc((size_t)NTOT * 4);
    int*      histS = (int*)alloc((size_t)NTOT * 4);
    unsigned* binned= (unsigned*)alloc((size_t)EP * 4);
    int*      csr   = (int*)alloc((size_t)EP * 4);
    _Float16* W1T   = (_Float16*)alloc((size_t)144 * 128 * 2);  // 128 cols + 4 att cols + 12 zero
    _Float16* W2T   = (_Float16*)alloc((size_t)16 * 128 * 2);   // 4 folded cols + 12 zero

    prep_kernel<<<81, 256, 0, stream>>>(W1, W2, att_src1, att_dst1, att_src2, att_dst2,
                                        b2, lw, W1T, W2T, cvec);
    hist_kernel<<<NB2, 256, 0, stream>>>(ei, hist);
    scan2_kernel<<<1, 1024, 0, stream>>>(hist, histS);
    scatterbin_kernel<<<NB2, 256, 0, stream>>>(ei, histS, binned);
    binsort_kernel<<<NBIN, 1024, 0, stream>>>(binned, histS, off, csr);
    gemm1_kernel<<<(N_NODES + 63) / 64, 256, 0, stream>>>(x, W1T, xw1q, asp1, ad1);
    agg1_kernel<<<N_NODES / 16, 256, 0, stream>>>(off, csr, asp1, ad1, xw1q, b1, h);
    gemm2_kernel<<<(N_NODES + 63) / 64, 256, 0, stream>>>(h, W2T, asp2);
    agg2_kernel<<<N_NODES / 16, 256, 0, stream>>>(off, csr, asp2, cvec, u, v);
    decode_kernel<<<(2 * P_CAND + 255) / 256, 256, 0, stream>>>(pos_ei, neg_ei, u, v, lb, out);
}

// Round 9
// 270.779 us; speedup vs baseline: 1.3944x; 1.0678x over previous
//
#include <hip/hip_runtime.h>

#define N_NODES 100000
#define E_EDGES 1600000
#define EP      (E_EDGES + N_NODES)   // edges + self loops = 1,700,000
#define P_CAND  262144
#define IN_C    128
#define HID     64
#define NEG_SLOPE 0.2f

#define NBIN  196            // ceil(100000/512) bins of 512 nodes
#define NB2   256            // blocks for hist/scatterbin
#define EPB   ((EP + NB2 - 1) / NB2)   // 6641 edges per block
#define NTOT  (NBIN * NB2)   // 50176

typedef _Float16 half4v __attribute__((ext_vector_type(4)));
typedef _Float16 half8v __attribute__((ext_vector_type(8)));
typedef float    float4v __attribute__((ext_vector_type(4)));

// ---------------- CSR build: deterministic 2-level counting sort ----------------

__global__ __launch_bounds__(256) void hist_kernel(const int* __restrict__ ei,
                                                   int* __restrict__ hist) {
    __shared__ int lh[NBIN];
    for (int t = threadIdx.x; t < NBIN; t += 256) lh[t] = 0;
    __syncthreads();
    int start = blockIdx.x * EPB;
    int end = min(start + EPB, EP);
    for (int i = start + threadIdx.x; i < end; i += 256) {
        int dst = (i < E_EDGES) ? ei[E_EDGES + i] : (i - E_EDGES);
        atomicAdd(&lh[dst >> 9], 1);
    }
    __syncthreads();
    for (int t = threadIdx.x; t < NBIN; t += 256) hist[t * NB2 + blockIdx.x] = lh[t];
}

// scanA: per-bin exclusive scan across the 256 block-columns (wave shfl scan, 1 barrier)
__global__ __launch_bounds__(256) void scanA_kernel(const int* __restrict__ hist,
                                                    int* __restrict__ rowscan,
                                                    int* __restrict__ binsum) {
    int t = blockIdx.x;            // bin 0..195
    int c = threadIdx.x;           // col 0..255
    int v = hist[t * NB2 + c];
    int lane = c & 63, w = c >> 6;
    int iv = v;
#pragma unroll
    for (int d = 1; d < 64; d <<= 1) {
        int o = __shfl_up(iv, d);
        if (lane >= d) iv += o;
    }
    __shared__ int wt[4];
    if (lane == 63) wt[w] = iv;
    __syncthreads();
    int add = 0;
    for (int i = 0; i < w; i++) add += wt[i];
    int inc = iv + add;
    rowscan[t * NB2 + c] = inc - v;             // exclusive within bin row
    if (c == 255) binsum[t] = inc;
}

// scanB: exclusive scan of the 196 bin totals -> binoff[0..196]
__global__ __launch_bounds__(256) void scanB_kernel(const int* __restrict__ binsum,
                                                    int* __restrict__ binoff) {
    __shared__ int s[256];
    int c = threadIdx.x;
    int v = (c < NBIN) ? binsum[c] : 0;
    s[c] = v;
    __syncthreads();
    for (int d = 1; d < 256; d <<= 1) {
        int o = (c >= d) ? s[c - d] : 0;
        __syncthreads();
        s[c] += o;
        __syncthreads();
    }
    if (c == 0) binoff[0] = 0;
    if (c < NBIN) binoff[c + 1] = s[c];          // binoff[NBIN] == EP
}

__global__ __launch_bounds__(256) void scatterbin_kernel(const int* __restrict__ ei,
                                                         const int* __restrict__ rowscan,
                                                         const int* __restrict__ binoff,
                                                         unsigned* __restrict__ binned) {
    __shared__ int cur[NBIN];
    for (int t = threadIdx.x; t < NBIN; t += 256)
        cur[t] = binoff[t] + rowscan[t * NB2 + blockIdx.x];
    __syncthreads();
    int start = blockIdx.x * EPB;
    int end = min(start + EPB, EP);
    for (int i = start + threadIdx.x; i < end; i += 256) {
        int src, dst;
        if (i < E_EDGES) { src = ei[i]; dst = ei[E_EDGES + i]; }
        else             { src = i - E_EDGES; dst = src; }
        int pos = atomicAdd(&cur[dst >> 9], 1);
        binned[pos] = (unsigned)src | ((unsigned)(dst & 511) << 17);
    }
}

__global__ __launch_bounds__(1024) void binsort_kernel(const unsigned* __restrict__ binned,
                                                       const int* __restrict__ binoff,
                                                       int* __restrict__ off,
                                                       int* __restrict__ csr) {
    __shared__ int lh[512];
    __shared__ int wpre[8];
    int b = blockIdx.x, t = threadIdx.x;
    int base = binoff[b];
    int endv = binoff[b + 1];
    if (t < 512) lh[t] = 0;
    __syncthreads();
    for (int i = base + t; i < endv; i += 1024)
        atomicAdd(&lh[binned[i] >> 17], 1);
    __syncthreads();
    // exclusive scan of lh[0..511]: wave shfl scan + 8-value fixup (3 barriers total)
    int iv = 0, lane = t & 63, w = t >> 6;
    if (t < 512) {
        iv = lh[t];
#pragma unroll
        for (int d = 1; d < 64; d <<= 1) {
            int o = __shfl_up(iv, d);
            if (lane >= d) iv += o;
        }
        if (lane == 63) wpre[w] = iv;
    }
    __syncthreads();
    if (t == 0) {
        int run = 0;
        for (int i = 0; i < 8; i++) { int x = wpre[i]; wpre[i] = run; run += x; }
    }
    __syncthreads();
    if (t < 512) {
        int ex = iv + wpre[w] - lh[t];
        int node = b * 512 + t;
        if (node <= N_NODES) off[node] = base + ex;
        lh[t] = base + ex;
    }
    __syncthreads();
    for (int i = base + t; i < endv; i += 1024) {
        unsigned v = binned[i];
        int pos = atomicAdd(&lh[v >> 17], 1);
        csr[pos] = (int)(v & 0x1FFFFu);
    }
}

// ---- Weight prep ----
// W1T: [col][k], col 0..143 (128 real, 4 att-dot cols, 12 zero pad)
// W2T: [col][k], col 0..15: 0=W2·a_src2 1=W2·a_dst2 2=W2·lw1 3=W2·lw2, 4..15 zero
// cvec: (b2·lw1, b2·lw2)

__global__ __launch_bounds__(256) void prep_kernel(
        const float* __restrict__ W1, const float* __restrict__ W2,
        const float* __restrict__ att_src1, const float* __restrict__ att_dst1,
        const float* __restrict__ att_src2, const float* __restrict__ att_dst2,
        const float* __restrict__ b2, const float* __restrict__ lw,
        _Float16* __restrict__ W1T, _Float16* __restrict__ W2T,
        float* __restrict__ cvec) {
    int idx = blockIdx.x * 256 + threadIdx.x;
    if (idx < 16384) {
        int col = idx >> 7, k = idx & 127;
        W1T[idx] = (_Float16)W1[k * 128 + col];
    } else if (idx < 16896) {
        int j = idx - 16384;
        int c4 = j >> 7, k = j & 127;   // c4: 0=as_h0 1=as_h1 2=ad_h0 3=ad_h1
        const float* av = (c4 < 2 ? att_src1 : att_dst1) + (c4 & 1) * 64;
        const float* wr = W1 + k * 128 + (c4 & 1) * 64;
        float s = 0.f;
        for (int c = 0; c < 64; c++) s += wr[c] * av[c];
        W1T[(128 + c4) * 128 + k] = (_Float16)s;
    } else if (idx < 18432) {
        W1T[132 * 128 + (idx - 16896)] = (_Float16)0.f;
    } else if (idx < 18944) {
        int j = idx - 18432;
        int c4 = j >> 7, k = j & 127;   // 0=as2 1=ad2 2=p1 3=p2
        const float* av = (c4 == 0) ? att_src2 : (c4 == 1) ? att_dst2
                        : (c4 == 2) ? lw : (lw + 64);
        const float* wr = W2 + k * 64;
        float s = 0.f;
        for (int c = 0; c < 64; c++) s += wr[c] * av[c];
        W2T[c4 * 128 + k] = (_Float16)s;
    } else if (idx < 20480) {
        W2T[512 + (idx - 18944)] = (_Float16)0.f;   // cols 4..15 zero
    } else if (idx < 20482) {
        int c = idx - 20480;                         // 0: b2·lw1, 1: b2·lw2
        const float* lwp = lw + c * 64;
        float s = 0.f;
        for (int i = 0; i < 64; i++) s += b2[i] * lwp[i];
        cvec[c] = s;
    }
}

// -------- Layer 1 GEMM: direct-to-register fragments, att folded into MFMA --------
// Epilogue: per-row int8 quantization; packs (as_h0, as_h1, scale) into asp1 float4.

__global__ __launch_bounds__(256) void gemm1_kernel(
        const float* __restrict__ x, const _Float16* __restrict__ W1T,
        unsigned char* __restrict__ xw1q, float* __restrict__ asp1,
        float* __restrict__ ad1) {
    __shared__ _Float16 xs[64 * 136];       // output transpose only
    int tid = threadIdx.x;
    int base = blockIdx.x * 64;
    int w = tid >> 6, l = tid & 63;
    int quad = l >> 4, lq = l & 15;
    int row = base + 16 * w + lq;
    size_t rb = (size_t)(row < N_NODES ? row : 0) * 32;   // float4 units
    const float4* x4 = (const float4*)x;
    float4 af[8];
#pragma unroll
    for (int ks = 0; ks < 4; ks++) {
        af[2 * ks]     = x4[rb + ks * 8 + quad * 2];
        af[2 * ks + 1] = x4[rb + ks * 8 + quad * 2 + 1];
    }
    half8v a[4];
#pragma unroll
    for (int ks = 0; ks < 4; ks++) {
        float4 u0 = af[2 * ks], u1 = af[2 * ks + 1];
        half8v t;
        t[0] = (_Float16)u0.x; t[1] = (_Float16)u0.y; t[2] = (_Float16)u0.z; t[3] = (_Float16)u0.w;
        t[4] = (_Float16)u1.x; t[5] = (_Float16)u1.y; t[6] = (_Float16)u1.z; t[7] = (_Float16)u1.w;
        a[ks] = t;
    }
    float4v acc[9];
#pragma unroll
    for (int t = 0; t < 9; t++) acc[t] = (float4v)0.f;
#pragma unroll
    for (int ks = 0; ks < 4; ++ks) {
#pragma unroll
        for (int t = 0; t < 9; t++) {
            half8v b = *(const half8v*)&W1T[(t * 16 + lq) * 128 + ks * 32 + quad * 8];
            acc[t] = __builtin_amdgcn_mfma_f32_16x16x32_f16(a[ks], b, acc[t], 0, 0, 0);
        }
    }
    // attention dots from MFMA tile t=8 (cols 128..131), lanes lq 0..3
    if (lq < 4) {
#pragma unroll
        for (int r = 0; r < 4; r++) {
            int n = base + 16 * w + quad * 4 + r;
            if (n < N_NODES) {
                if (lq < 2) asp1[4 * n + lq] = acc[8][r];          // as_h0, as_h1
                else        ad1[2 * n + (lq & 1)] = acc[8][r];     // ad_h0, ad_h1
            }
        }
    }
    // transpose via LDS
#pragma unroll
    for (int t = 0; t < 8; t++)
#pragma unroll
        for (int r = 0; r < 4; r++)
            xs[(16 * w + quad * 4 + r) * 136 + t * 16 + lq] = (_Float16)acc[t][r];
    __syncthreads();
    // int8 row quantization: 4 lanes per node, 32 cols each
    int node = tid >> 2, seg = tid & 3;
    if (base + node < N_NODES) {
        float vals[32];
        float mx = 0.f;
#pragma unroll
        for (int i = 0; i < 4; i++) {
            half8v vv = *(const half8v*)&xs[node * 136 + seg * 32 + i * 8];
#pragma unroll
            for (int k = 0; k < 8; k++) {
                float f = (float)vv[k];
                vals[i * 8 + k] = f;
                mx = fmaxf(mx, fabsf(f));
            }
        }
        mx = fmaxf(mx, __shfl_xor(mx, 1));   // 4 lanes of a node are consecutive
        mx = fmaxf(mx, __shfl_xor(mx, 2));
        mx = fmaxf(mx, 1e-20f);
        float r = 127.f / mx;
        unsigned pk[8];
#pragma unroll
        for (int d = 0; d < 8; d++) {
            unsigned u0 = (unsigned)(__float2int_rn(vals[d * 4 + 0] * r) + 128);
            unsigned u1 = (unsigned)(__float2int_rn(vals[d * 4 + 1] * r) + 128);
            unsigned u2 = (unsigned)(__float2int_rn(vals[d * 4 + 2] * r) + 128);
            unsigned u3 = (unsigned)(__float2int_rn(vals[d * 4 + 3] * r) + 128);
            pk[d] = u0 | (u1 << 8) | (u2 << 16) | (u3 << 24);
        }
        unsigned* dst = (unsigned*)&xw1q[(size_t)(base + node) * 128 + seg * 32];
        *(uint4*)dst       = make_uint4(pk[0], pk[1], pk[2], pk[3]);
        *(uint4*)(dst + 4) = make_uint4(pk[4], pk[5], pk[6], pk[7]);
        if (seg == 0) asp1[4 * (base + node) + 2] = mx * (1.f / 127.f);
    }
}

// ---- Layer 1 aggregation: 16-lane groups, int8 dequant, pre-scaled LDS records ----
// sum f*w = sum g*u - 128*sum g  where g = f*scale (pre-folded in esm).

__global__ __launch_bounds__(256) void agg1_kernel(
        const int* __restrict__ off, const int* __restrict__ csr_src,
        const float* __restrict__ asp1, const float* __restrict__ ad1,
        const unsigned char* __restrict__ xw1q, const float* __restrict__ b1,
        _Float16* __restrict__ h) {
    __shared__ float2 esm[4][64];           // per-wave (g0, g1) records
    int wv = threadIdx.x >> 6, lane = threadIdx.x & 63;
    int ql = lane & 15;                     // edge lane within group == col-group (ql<8: head0)
    int gb = lane & 48;                     // group base lane
    int n = blockIdx.x * 16 + (wv << 2) + (lane >> 4);   // 16 nodes/block, exact at 6250 blocks
    int s = off[n], e = off[n + 1];
    float2 ad = *(const float2*)&ad1[2 * n];
    float adn0 = ad.x, adn1 = ad.y;
    const char* fl = (const char*)&esm[wv][gb] + ((ql >= 8) ? 4 : 0);
    const unsigned char* xq = xw1q + 8 * ql; // 8 u8 cols per lane
    float acc[8];
#pragma unroll
    for (int i = 0; i < 8; i++) acc[i] = 0.f;
    float sl0 = 0.f, sl1 = 0.f;             // per-lane denominator partials
    float csum = 0.f;                       // sum of g (per-lane head-specific)

#define DEQ1(QV, G) { \
    acc[0] = fmaf((float)((QV).x & 0xffu), (G), acc[0]); \
    acc[1] = fmaf((float)(((QV).x >> 8) & 0xffu), (G), acc[1]); \
    acc[2] = fmaf((float)(((QV).x >> 16) & 0xffu), (G), acc[2]); \
    acc[3] = fmaf((float)((QV).x >> 24), (G), acc[3]); \
    acc[4] = fmaf((float)((QV).y & 0xffu), (G), acc[4]); \
    acc[5] = fmaf((float)(((QV).y >> 8) & 0xffu), (G), acc[5]); \
    acc[6] = fmaf((float)(((QV).y >> 16) & 0xffu), (G), acc[6]); \
    acc[7] = fmaf((float)((QV).y >> 24), (G), acc[7]); }

    for (int b = s; b < e; b += 16) {
        int cnt = min(16, e - b);
        int l = ql < cnt ? ql : cnt - 1;
        int srcv = csr_src[b + l];
        float4 ap = *(const float4*)&asp1[4 * srcv];   // (as0, as1, scl, -) one 16B load
        float e0 = ap.x + adn0; e0 = e0 > 0.f ? e0 : NEG_SLOPE * e0;
        float e1 = ap.y + adn1; e1 = e1 > 0.f ? e1 : NEG_SLOPE * e1;
        float f0v = (ql < cnt) ? __expf(e0) : 0.f;
        float f1v = (ql < cnt) ? __expf(e1) : 0.f;
        sl0 += f0v; sl1 += f1v;
        esm[wv][lane] = make_float2(f0v * ap.z, f1v * ap.z);   // pre-scaled
        // 2-deep rotation over this chunk's edges (group-uniform trip count)
        int sj = __shfl(srcv, gb);
        uint2 qcur = *(const uint2*)&xq[(size_t)sj * 128];
        int j = 0;
        for (; j + 1 < cnt; ++j) {
            int sn = __shfl(srcv, gb + j + 1);
            uint2 qnxt = *(const uint2*)&xq[(size_t)sn * 128];
            float g = *(const float*)(fl + (size_t)j * 8);
            csum += g;
            DEQ1(qcur, g)
            qcur = qnxt;
        }
        { float g = *(const float*)(fl + (size_t)j * 8);
          csum += g; DEQ1(qcur, g) }
    }
#undef DEQ1
    // denominator reduce within 16-lane group
#pragma unroll
    for (int m = 8; m >= 1; m >>= 1) { sl0 += __shfl_xor(sl0, m); sl1 += __shfl_xor(sl1, m); }
    float sum = (ql >= 8) ? sl1 : sl0;
    float rs = __builtin_amdgcn_rcpf(sum);  // ~1 ulp, << storage quant error
    float base8 = -128.f * csum;
    int c = 8 * ql;
    half8v o;
#pragma unroll
    for (int i = 0; i < 8; i++) {
        float vv = fmaf(acc[i] + base8, rs, b1[c + i]);
        o[i] = (_Float16)(vv > 0.f ? vv : 0.f);   // relu
    }
    *(half8v*)&h[(size_t)n * 128 + c] = o;
}

// -------- Layer 2 GEMM: single 4-col MFMA tile -> asp2 = (as2, p1, p2, ad2) --------

__global__ __launch_bounds__(256) void gemm2_kernel(
        const _Float16* __restrict__ h, const _Float16* __restrict__ W2T,
        float* __restrict__ asp2) {
    int tid = threadIdx.x;
    int base = blockIdx.x * 64;
    int w = tid >> 6, l = tid & 63;
    int quad = l >> 4, lq = l & 15;
    int row = base + 16 * w + lq;
    size_t rbase = (size_t)(row < N_NODES ? row : 0) * 128;
    half8v a[4];
#pragma unroll
    for (int ks = 0; ks < 4; ks++)
        a[ks] = *(const half8v*)&h[rbase + ks * 32 + quad * 8];
    float4v acc = (float4v)0.f;
#pragma unroll
    for (int ks = 0; ks < 4; ++ks) {
        half8v b = *(const half8v*)&W2T[lq * 128 + ks * 32 + quad * 8];
        acc = __builtin_amdgcn_mfma_f32_16x16x32_f16(a[ks], b, acc, 0, 0, 0);
    }
    // cols: lq0=as2 lq1=ad2 lq2=p1 lq3=p2 -> asp2 slots (.x=as2,.y=p1,.z=p2,.w=ad2)
    if (lq < 4) {
        int slot = (lq == 0) ? 0 : (lq == 1) ? 3 : (lq == 2) ? 1 : 2;
#pragma unroll
        for (int r = 0; r < 4; r++) {
            int n = base + 16 * w + quad * 4 + r;
            if (n < N_NODES) asp2[4 * n + slot] = acc[r];
        }
    }
}

// ---- Layer 2 aggregation: scalar-only gather (16B/edge, L2-resident table) ----

__global__ __launch_bounds__(256) void agg2_kernel(
        const int* __restrict__ off, const int* __restrict__ csr_src,
        const float* __restrict__ asp2, const float* __restrict__ cvec,
        float* __restrict__ u, float* __restrict__ v) {
    int wv = threadIdx.x >> 6, lane = threadIdx.x & 63;
    int ql = lane & 15;
    int n = blockIdx.x * 16 + (wv << 2) + (lane >> 4);   // 16 nodes/block, exact at 6250 blocks
    int s = off[n], e = off[n + 1];
    float adn = asp2[4 * n + 3];            // ad2 of dst node
    float sf = 0.f, s1 = 0.f, s2 = 0.f;
    for (int j = s + ql; j < e; j += 16) {
        int srcv = csr_src[j];
        float4 ap = *(const float4*)&asp2[4 * srcv];
        float ev = ap.x + adn; ev = ev > 0.f ? ev : NEG_SLOPE * ev;
        float f = __expf(ev);
        sf += f;
        s1 = fmaf(f, ap.y, s1);
        s2 = fmaf(f, ap.z, s2);
    }
#pragma unroll
    for (int m = 8; m >= 1; m >>= 1) {
        sf += __shfl_xor(sf, m);
        s1 += __shfl_xor(s1, m);
        s2 += __shfl_xor(s2, m);
    }
    if (ql == 0) {
        float rs = __builtin_amdgcn_rcpf(sf);
        u[n] = fmaf(s1, rs, cvec[0]);
        v[n] = fmaf(s2, rs, cvec[1]);
    }
}

// ---------------- Link decode: out = u[s] + v[d] + lb ----------------

__global__ __launch_bounds__(256) void decode_kernel(
        const int* __restrict__ pos_ei, const int* __restrict__ neg_ei,
        const float* __restrict__ u, const float* __restrict__ v,
        const float* __restrict__ lb, float* __restrict__ out) {
    int idx = blockIdx.x * 256 + threadIdx.x;
    if (idx >= 2 * P_CAND) return;
    const int* ei; int p;
    if (idx < P_CAND) { ei = pos_ei; p = idx; }
    else              { ei = neg_ei; p = idx - P_CAND; }
    int sN = ei[p], dN = ei[P_CAND + p];
    out[idx] = u[sN] + v[dN] + lb[0];
}

// ---------------- launch ----------------

extern "C" void kernel_launch(void* const* d_in, const int* in_sizes, int n_in,
                              void* d_out, int out_size, void* d_ws, size_t ws_size,
                              hipStream_t stream) {
    const float* x        = (const float*)d_in[0];
    const int*   ei       = (const int*)d_in[1];
    const int*   pos_ei   = (const int*)d_in[3];
    const int*   neg_ei   = (const int*)d_in[4];
    const float* W1       = (const float*)d_in[5];
    const float* att_src1 = (const float*)d_in[6];
    const float* att_dst1 = (const float*)d_in[7];
    const float* b1       = (const float*)d_in[8];
    const float* W2       = (const float*)d_in[9];
    const float* att_src2 = (const float*)d_in[10];
    const float* att_dst2 = (const float*)d_in[11];
    const float* b2       = (const float*)d_in[12];
    const float* lw       = (const float*)d_in[13];
    const float* lb       = (const float*)d_in[14];
    float* out = (float*)d_out;

    char* ws = (char*)d_ws;
    size_t o = 0;
    auto alloc = [&](size_t bytes) -> char* {
        char* p = ws + o;
        o += (bytes + 511) & ~(size_t)511;
        return p;
    };
    unsigned char* xw1q = (unsigned char*)alloc((size_t)N_NODES * 128);   // int8 table
    float*    asp1  = (float*)alloc((size_t)N_NODES * 4 * 4);   // (as0, as1, scl, -)
    float*    ad1   = (float*)alloc((size_t)N_NODES * 2 * 4);
    _Float16* h     = (_Float16*)alloc((size_t)N_NODES * 128 * 2 + 16384); // +slack for OOB-safe reads
    float*    asp2  = (float*)alloc((size_t)N_NODES * 4 * 4);   // (as2, p1, p2, ad2)
    float*    cvec  = (float*)alloc(512);
    float*    u     = (float*)alloc((size_t)N_NODES * 4);
    float*    v     = (float*)alloc((size_t)N_NODES * 4);
    int*      off   = (int*)alloc((size_t)(N_NODES + 1) * 4);
    int*      hist  = (int*)alloc((size_t)NTOT * 4);
    int*      rowscan = (int*)alloc((size_t)NTOT * 4);
    int*      binsum  = (int*)alloc(256 * 4);
    int*      binoff  = (int*)alloc(256 * 4);
    unsigned* binned= (unsigned*)alloc((size_t)EP * 4);
    int*      csr   = (int*)alloc((size_t)EP * 4);
    _Float16* W1T   = (_Float16*)alloc((size_t)144 * 128 * 2);  // 128 cols + 4 att cols + 12 zero
    _Float16* W2T   = (_Float16*)alloc((size_t)16 * 128 * 2);   // 4 folded cols + 12 zero

    prep_kernel<<<81, 256, 0, stream>>>(W1, W2, att_src1, att_dst1, att_src2, att_dst2,
                                        b2, lw, W1T, W2T, cvec);
    hist_kernel<<<NB2, 256, 0, stream>>>(ei, hist);
    scanA_kernel<<<NBIN, 256, 0, stream>>>(hist, rowscan, binsum);
    scanB_kernel<<<1, 256, 0, stream>>>(binsum, binoff);
    scatterbin_kernel<<<NB2, 256, 0, stream>>>(ei, rowscan, binoff, binned);
    binsort_kernel<<<NBIN, 1024, 0, stream>>>(binned, binoff, off, csr);
    gemm1_kernel<<<(N_NODES + 63) / 64, 256, 0, stream>>>(x, W1T, xw1q, asp1, ad1);
    agg1_kernel<<<N_NODES / 16, 256, 0, stream>>>(off, csr, asp1, ad1, xw1q, b1, h);
    gemm2_kernel<<<(N_NODES + 63) / 64, 256, 0, stream>>>(h, W2T, asp2);
    agg2_kernel<<<N_NODES / 16, 256, 0, stream>>>(off, csr, asp2, cvec, u, v);
    decode_kernel<<<(2 * P_CAND + 255) / 256, 256, 0, stream>>>(pos_ei, neg_ei, u, v, lb, out);
}

// Round 10
// 262.856 us; speedup vs baseline: 1.4365x; 1.0301x over previous
//
#include <hip/hip_runtime.h>

#define N_NODES 100000
#define E_EDGES 1600000
#define EP      (E_EDGES + N_NODES)   // edges + self loops = 1,700,000
#define P_CAND  262144
#define IN_C    128
#define HID     64
#define NEG_SLOPE 0.2f

#define NBIN  196            // ceil(100000/512) bins of 512 nodes
#define NB2   256            // blocks for hist/scatterbin
#define EPB   ((EP + NB2 - 1) / NB2)   // 6641 edges per block
#define NTOT  (NBIN * NB2)   // 50176

typedef _Float16 half4v __attribute__((ext_vector_type(4)));
typedef _Float16 half8v __attribute__((ext_vector_type(8)));
typedef float    float4v __attribute__((ext_vector_type(4)));

// ---------------- CSR build: deterministic 2-level counting sort ----------------

__global__ __launch_bounds__(256) void hist_kernel(const int* __restrict__ ei,
                                                   int* __restrict__ hist) {
    __shared__ int lh[NBIN];
    for (int t = threadIdx.x; t < NBIN; t += 256) lh[t] = 0;
    __syncthreads();
    int start = blockIdx.x * EPB;
    int end = min(start + EPB, EP);
    for (int i = start + threadIdx.x; i < end; i += 256) {
        int dst = (i < E_EDGES) ? ei[E_EDGES + i] : (i - E_EDGES);
        atomicAdd(&lh[dst >> 9], 1);
    }
    __syncthreads();
    for (int t = threadIdx.x; t < NBIN; t += 256) hist[t * NB2 + blockIdx.x] = lh[t];
}

// scanA: per-bin exclusive scan across the 256 block-columns (wave shfl scan, 1 barrier)
__global__ __launch_bounds__(256) void scanA_kernel(const int* __restrict__ hist,
                                                    int* __restrict__ rowscan,
                                                    int* __restrict__ binsum) {
    int t = blockIdx.x;            // bin 0..195
    int c = threadIdx.x;           // col 0..255
    int v = hist[t * NB2 + c];
    int lane = c & 63, w = c >> 6;
    int iv = v;
#pragma unroll
    for (int d = 1; d < 64; d <<= 1) {
        int o = __shfl_up(iv, d);
        if (lane >= d) iv += o;
    }
    __shared__ int wt[4];
    if (lane == 63) wt[w] = iv;
    __syncthreads();
    int add = 0;
    for (int i = 0; i < w; i++) add += wt[i];
    int inc = iv + add;
    rowscan[t * NB2 + c] = inc - v;             // exclusive within bin row
    if (c == 255) binsum[t] = inc;
}

// scanB: exclusive scan of the 196 bin totals -> binoff[0..196]
__global__ __launch_bounds__(256) void scanB_kernel(const int* __restrict__ binsum,
                                                    int* __restrict__ binoff) {
    __shared__ int s[256];
    int c = threadIdx.x;
    int v = (c < NBIN) ? binsum[c] : 0;
    s[c] = v;
    __syncthreads();
    for (int d = 1; d < 256; d <<= 1) {
        int o = (c >= d) ? s[c - d] : 0;
        __syncthreads();
        s[c] += o;
        __syncthreads();
    }
    if (c == 0) binoff[0] = 0;
    if (c < NBIN) binoff[c + 1] = s[c];          // binoff[NBIN] == EP
}

__global__ __launch_bounds__(256) void scatterbin_kernel(const int* __restrict__ ei,
                                                         const int* __restrict__ rowscan,
                                                         const int* __restrict__ binoff,
                                                         unsigned* __restrict__ binned) {
    __shared__ int cur[NBIN];
    for (int t = threadIdx.x; t < NBIN; t += 256)
        cur[t] = binoff[t] + rowscan[t * NB2 + blockIdx.x];
    __syncthreads();
    int start = blockIdx.x * EPB;
    int end = min(start + EPB, EP);
    for (int i = start + threadIdx.x; i < end; i += 256) {
        int src, dst;
        if (i < E_EDGES) { src = ei[i]; dst = ei[E_EDGES + i]; }
        else             { src = i - E_EDGES; dst = src; }
        int pos = atomicAdd(&cur[dst >> 9], 1);
        binned[pos] = (unsigned)src | ((unsigned)(dst & 511) << 17);
    }
}

__global__ __launch_bounds__(1024) void binsort_kernel(const unsigned* __restrict__ binned,
                                                       const int* __restrict__ binoff,
                                                       int* __restrict__ off,
                                                       int* __restrict__ csr) {
    __shared__ int lh[512];
    __shared__ int wpre[8];
    int b = blockIdx.x, t = threadIdx.x;
    int base = binoff[b];
    int endv = binoff[b + 1];
    if (t < 512) lh[t] = 0;
    __syncthreads();
    for (int i = base + t; i < endv; i += 1024)
        atomicAdd(&lh[binned[i] >> 17], 1);
    __syncthreads();
    // exclusive scan of lh[0..511]: wave shfl scan + 8-value fixup (3 barriers total)
    int iv = 0, lane = t & 63, w = t >> 6;
    if (t < 512) {
        iv = lh[t];
#pragma unroll
        for (int d = 1; d < 64; d <<= 1) {
            int o = __shfl_up(iv, d);
            if (lane >= d) iv += o;
        }
        if (lane == 63) wpre[w] = iv;
    }
    __syncthreads();
    if (t == 0) {
        int run = 0;
        for (int i = 0; i < 8; i++) { int x = wpre[i]; wpre[i] = run; run += x; }
    }
    __syncthreads();
    if (t < 512) {
        int ex = iv + wpre[w] - lh[t];
        int node = b * 512 + t;
        if (node <= N_NODES) off[node] = base + ex;
        lh[t] = base + ex;
    }
    __syncthreads();
    for (int i = base + t; i < endv; i += 1024) {
        unsigned v = binned[i];
        int pos = atomicAdd(&lh[v >> 17], 1);
        csr[pos] = (int)(v & 0x1FFFFu);
    }
}

// ---- Weight prep ----
// W1T: [col][k], col 0..143 (128 real, 4 att-dot cols, 12 zero pad)
// W2T: [col][k], col 0..3: 0=W2·a_src2 1=W2·a_dst2 2=W2·lw1 3=W2·lw2
// cvec: (b2·lw1, b2·lw2)

__global__ __launch_bounds__(256) void prep_kernel(
        const float* __restrict__ W1, const float* __restrict__ W2,
        const float* __restrict__ att_src1, const float* __restrict__ att_dst1,
        const float* __restrict__ att_src2, const float* __restrict__ att_dst2,
        const float* __restrict__ b2, const float* __restrict__ lw,
        _Float16* __restrict__ W1T, _Float16* __restrict__ W2T,
        float* __restrict__ cvec) {
    int idx = blockIdx.x * 256 + threadIdx.x;
    if (idx < 16384) {
        int col = idx >> 7, k = idx & 127;
        W1T[idx] = (_Float16)W1[k * 128 + col];
    } else if (idx < 16896) {
        int j = idx - 16384;
        int c4 = j >> 7, k = j & 127;   // c4: 0=as_h0 1=as_h1 2=ad_h0 3=ad_h1
        const float* av = (c4 < 2 ? att_src1 : att_dst1) + (c4 & 1) * 64;
        const float* wr = W1 + k * 128 + (c4 & 1) * 64;
        float s = 0.f;
        for (int c = 0; c < 64; c++) s += wr[c] * av[c];
        W1T[(128 + c4) * 128 + k] = (_Float16)s;
    } else if (idx < 18432) {
        W1T[132 * 128 + (idx - 16896)] = (_Float16)0.f;
    } else if (idx < 18944) {
        int j = idx - 18432;
        int c4 = j >> 7, k = j & 127;   // 0=as2 1=ad2 2=p1 3=p2
        const float* av = (c4 == 0) ? att_src2 : (c4 == 1) ? att_dst2
                        : (c4 == 2) ? lw : (lw + 64);
        const float* wr = W2 + k * 64;
        float s = 0.f;
        for (int c = 0; c < 64; c++) s += wr[c] * av[c];
        W2T[c4 * 128 + k] = (_Float16)s;
    } else if (idx < 18946) {
        int c = idx - 18944;                         // 0: b2·lw1, 1: b2·lw2
        const float* lwp = lw + c * 64;
        float s = 0.f;
        for (int i = 0; i < 64; i++) s += b2[i] * lwp[i];
        cvec[c] = s;
    }
}

// -------- Layer 1 GEMM: direct-to-register fragments, att folded into MFMA --------
// Epilogue: per-row int8 quantization; packs (as_h0, as_h1, scale) into asp1 float4.

__global__ __launch_bounds__(256) void gemm1_kernel(
        const float* __restrict__ x, const _Float16* __restrict__ W1T,
        unsigned char* __restrict__ xw1q, float* __restrict__ asp1,
        float* __restrict__ ad1) {
    __shared__ _Float16 xs[64 * 136];       // output transpose only
    int tid = threadIdx.x;
    int base = blockIdx.x * 64;
    int w = tid >> 6, l = tid & 63;
    int quad = l >> 4, lq = l & 15;
    int row = base + 16 * w + lq;
    size_t rb = (size_t)(row < N_NODES ? row : 0) * 32;   // float4 units
    const float4* x4 = (const float4*)x;
    float4 af[8];
#pragma unroll
    for (int ks = 0; ks < 4; ks++) {
        af[2 * ks]     = x4[rb + ks * 8 + quad * 2];
        af[2 * ks + 1] = x4[rb + ks * 8 + quad * 2 + 1];
    }
    half8v a[4];
#pragma unroll
    for (int ks = 0; ks < 4; ks++) {
        float4 u0 = af[2 * ks], u1 = af[2 * ks + 1];
        half8v t;
        t[0] = (_Float16)u0.x; t[1] = (_Float16)u0.y; t[2] = (_Float16)u0.z; t[3] = (_Float16)u0.w;
        t[4] = (_Float16)u1.x; t[5] = (_Float16)u1.y; t[6] = (_Float16)u1.z; t[7] = (_Float16)u1.w;
        a[ks] = t;
    }
    float4v acc[9];
#pragma unroll
    for (int t = 0; t < 9; t++) acc[t] = (float4v)0.f;
#pragma unroll
    for (int ks = 0; ks < 4; ++ks) {
#pragma unroll
        for (int t = 0; t < 9; t++) {
            half8v b = *(const half8v*)&W1T[(t * 16 + lq) * 128 + ks * 32 + quad * 8];
            acc[t] = __builtin_amdgcn_mfma_f32_16x16x32_f16(a[ks], b, acc[t], 0, 0, 0);
        }
    }
    // attention dots from MFMA tile t=8 (cols 128..131), lanes lq 0..3
    if (lq < 4) {
#pragma unroll
        for (int r = 0; r < 4; r++) {
            int n = base + 16 * w + quad * 4 + r;
            if (n < N_NODES) {
                if (lq < 2) asp1[4 * n + lq] = acc[8][r];          // as_h0, as_h1
                else        ad1[2 * n + (lq & 1)] = acc[8][r];     // ad_h0, ad_h1
            }
        }
    }
    // transpose via LDS
#pragma unroll
    for (int t = 0; t < 8; t++)
#pragma unroll
        for (int r = 0; r < 4; r++)
            xs[(16 * w + quad * 4 + r) * 136 + t * 16 + lq] = (_Float16)acc[t][r];
    __syncthreads();
    // int8 row quantization: 4 lanes per node, 32 cols each
    int node = tid >> 2, seg = tid & 3;
    if (base + node < N_NODES) {
        float vals[32];
        float mx = 0.f;
#pragma unroll
        for (int i = 0; i < 4; i++) {
            half8v vv = *(const half8v*)&xs[node * 136 + seg * 32 + i * 8];
#pragma unroll
            for (int k = 0; k < 8; k++) {
                float f = (float)vv[k];
                vals[i * 8 + k] = f;
                mx = fmaxf(mx, fabsf(f));
            }
        }
        mx = fmaxf(mx, __shfl_xor(mx, 1));   // 4 lanes of a node are consecutive
        mx = fmaxf(mx, __shfl_xor(mx, 2));
        mx = fmaxf(mx, 1e-20f);
        float r = 127.f / mx;
        unsigned pk[8];
#pragma unroll
        for (int d = 0; d < 8; d++) {
            unsigned u0 = (unsigned)(__float2int_rn(vals[d * 4 + 0] * r) + 128);
            unsigned u1 = (unsigned)(__float2int_rn(vals[d * 4 + 1] * r) + 128);
            unsigned u2 = (unsigned)(__float2int_rn(vals[d * 4 + 2] * r) + 128);
            unsigned u3 = (unsigned)(__float2int_rn(vals[d * 4 + 3] * r) + 128);
            pk[d] = u0 | (u1 << 8) | (u2 << 16) | (u3 << 24);
        }
        unsigned* dst = (unsigned*)&xw1q[(size_t)(base + node) * 128 + seg * 32];
        *(uint4*)dst       = make_uint4(pk[0], pk[1], pk[2], pk[3]);
        *(uint4*)(dst + 4) = make_uint4(pk[4], pk[5], pk[6], pk[7]);
        if (seg == 0) asp1[4 * (base + node) + 2] = mx * (1.f / 127.f);
    }
}

// ---- Layer 1 aggregation + FUSED layer-2 projection ----
// agg: 16-lane groups, int8 dequant, pre-scaled LDS records.
// epilogue: z = relu(acc/sum + b1) stays in registers; dot with 4 folded W2T
// columns (as2, ad2, p1, p2) + 16-lane reduce -> asp2[n]. h never materialized.

__global__ __launch_bounds__(256) void agg1_kernel(
        const int* __restrict__ off, const int* __restrict__ csr_src,
        const float* __restrict__ asp1, const float* __restrict__ ad1,
        const unsigned char* __restrict__ xw1q, const float* __restrict__ b1,
        const _Float16* __restrict__ W2T, float* __restrict__ asp2) {
    __shared__ float2 esm[4][64];           // per-wave (g0, g1) records
    int wv = threadIdx.x >> 6, lane = threadIdx.x & 63;
    int ql = lane & 15;                     // edge lane within group == col-group (ql<8: head0)
    int gb = lane & 48;                     // group base lane
    int n = blockIdx.x * 16 + (wv << 2) + (lane >> 4);   // 16 nodes/block, exact at 6250 blocks
    int s = off[n], e = off[n + 1];
    float2 ad = *(const float2*)&ad1[2 * n];
    float adn0 = ad.x, adn1 = ad.y;
    const char* fl = (const char*)&esm[wv][gb] + ((ql >= 8) ? 4 : 0);
    const unsigned char* xq = xw1q + 8 * ql; // 8 u8 cols per lane
    float acc[8];
#pragma unroll
    for (int i = 0; i < 8; i++) acc[i] = 0.f;
    float sl0 = 0.f, sl1 = 0.f;             // per-lane denominator partials
    float csum = 0.f;                       // sum of g (per-lane head-specific)

#define DEQ1(QV, G) { \
    acc[0] = fmaf((float)((QV).x & 0xffu), (G), acc[0]); \
    acc[1] = fmaf((float)(((QV).x >> 8) & 0xffu), (G), acc[1]); \
    acc[2] = fmaf((float)(((QV).x >> 16) & 0xffu), (G), acc[2]); \
    acc[3] = fmaf((float)((QV).x >> 24), (G), acc[3]); \
    acc[4] = fmaf((float)((QV).y & 0xffu), (G), acc[4]); \
    acc[5] = fmaf((float)(((QV).y >> 8) & 0xffu), (G), acc[5]); \
    acc[6] = fmaf((float)(((QV).y >> 16) & 0xffu), (G), acc[6]); \
    acc[7] = fmaf((float)((QV).y >> 24), (G), acc[7]); }

    for (int b = s; b < e; b += 16) {
        int cnt = min(16, e - b);
        int l = ql < cnt ? ql : cnt - 1;
        int srcv = csr_src[b + l];
        float4 ap = *(const float4*)&asp1[4 * srcv];   // (as0, as1, scl, -) one 16B load
        float e0 = ap.x + adn0; e0 = e0 > 0.f ? e0 : NEG_SLOPE * e0;
        float e1 = ap.y + adn1; e1 = e1 > 0.f ? e1 : NEG_SLOPE * e1;
        float f0v = (ql < cnt) ? __expf(e0) : 0.f;
        float f1v = (ql < cnt) ? __expf(e1) : 0.f;
        sl0 += f0v; sl1 += f1v;
        esm[wv][lane] = make_float2(f0v * ap.z, f1v * ap.z);   // pre-scaled
        // 2-deep rotation over this chunk's edges (group-uniform trip count)
        int sj = __shfl(srcv, gb);
        uint2 qcur = *(const uint2*)&xq[(size_t)sj * 128];
        int j = 0;
        for (; j + 1 < cnt; ++j) {
            int sn = __shfl(srcv, gb + j + 1);
            uint2 qnxt = *(const uint2*)&xq[(size_t)sn * 128];
            float g = *(const float*)(fl + (size_t)j * 8);
            csum += g;
            DEQ1(qcur, g)
            qcur = qnxt;
        }
        { float g = *(const float*)(fl + (size_t)j * 8);
          csum += g; DEQ1(qcur, g) }
    }
#undef DEQ1
    // denominator reduce within 16-lane group
#pragma unroll
    for (int m = 8; m >= 1; m >>= 1) { sl0 += __shfl_xor(sl0, m); sl1 += __shfl_xor(sl1, m); }
    float sum = (ql >= 8) ? sl1 : sl0;
    float rs = __builtin_amdgcn_rcpf(sum);  // ~1 ulp, << storage quant error
    float base8 = -128.f * csum;
    int c = 8 * ql;
    // z fragment (fp32, this lane's 8 cols of the node's 128-wide h row)
    float z[8];
#pragma unroll
    for (int i = 0; i < 8; i++) {
        float vv = fmaf(acc[i] + base8, rs, b1[c + i]);
        z[i] = vv > 0.f ? vv : 0.f;         // relu
    }
    // fused layer-2 projection: dot z with 4 folded W2T columns
    half8v w0 = *(const half8v*)&W2T[0 * 128 + c];
    half8v w1 = *(const half8v*)&W2T[1 * 128 + c];
    half8v w2 = *(const half8v*)&W2T[2 * 128 + c];
    half8v w3 = *(const half8v*)&W2T[3 * 128 + c];
    float d0 = 0.f, d1 = 0.f, d2 = 0.f, d3 = 0.f;
#pragma unroll
    for (int i = 0; i < 8; i++) {
        d0 = fmaf(z[i], (float)w0[i], d0);
        d1 = fmaf(z[i], (float)w1[i], d1);
        d2 = fmaf(z[i], (float)w2[i], d2);
        d3 = fmaf(z[i], (float)w3[i], d3);
    }
#pragma unroll
    for (int m = 8; m >= 1; m >>= 1) {
        d0 += __shfl_xor(d0, m);
        d1 += __shfl_xor(d1, m);
        d2 += __shfl_xor(d2, m);
        d3 += __shfl_xor(d3, m);
    }
    if (ql == 0) {
        // asp2 layout: (.x=as2, .y=p1, .z=p2, .w=ad2)
        *(float4*)&asp2[4 * n] = make_float4(d0, d2, d3, d1);
    }
}

// ---- Layer 2 aggregation: scalar-only gather (16B/edge, L2-resident table) ----

__global__ __launch_bounds__(256) void agg2_kernel(
        const int* __restrict__ off, const int* __restrict__ csr_src,
        const float* __restrict__ asp2, const float* __restrict__ cvec,
        float* __restrict__ u, float* __restrict__ v) {
    int wv = threadIdx.x >> 6, lane = threadIdx.x & 63;
    int ql = lane & 15;
    int n = blockIdx.x * 16 + (wv << 2) + (lane >> 4);   // 16 nodes/block, exact at 6250 blocks
    int s = off[n], e = off[n + 1];
    float adn = asp2[4 * n + 3];            // ad2 of dst node
    float sf = 0.f, s1 = 0.f, s2 = 0.f;
    for (int j = s + ql; j < e; j += 16) {
        int srcv = csr_src[j];
        float4 ap = *(const float4*)&asp2[4 * srcv];
        float ev = ap.x + adn; ev = ev > 0.f ? ev : NEG_SLOPE * ev;
        float f = __expf(ev);
        sf += f;
        s1 = fmaf(f, ap.y, s1);
        s2 = fmaf(f, ap.z, s2);
    }
#pragma unroll
    for (int m = 8; m >= 1; m >>= 1) {
        sf += __shfl_xor(sf, m);
        s1 += __shfl_xor(s1, m);
        s2 += __shfl_xor(s2, m);
    }
    if (ql == 0) {
        float rs = __builtin_amdgcn_rcpf(sf);
        u[n] = fmaf(s1, rs, cvec[0]);
        v[n] = fmaf(s2, rs, cvec[1]);
    }
}

// ---------------- Link decode: out = u[s] + v[d] + lb ----------------

__global__ __launch_bounds__(256) void decode_kernel(
        const int* __restrict__ pos_ei, const int* __restrict__ neg_ei,
        const float* __restrict__ u, const float* __restrict__ v,
        const float* __restrict__ lb, float* __restrict__ out) {
    int idx = blockIdx.x * 256 + threadIdx.x;
    if (idx >= 2 * P_CAND) return;
    const int* ei; int p;
    if (idx < P_CAND) { ei = pos_ei; p = idx; }
    else              { ei = neg_ei; p = idx - P_CAND; }
    int sN = ei[p], dN = ei[P_CAND + p];
    out[idx] = u[sN] + v[dN] + lb[0];
}

// ---------------- launch ----------------

extern "C" void kernel_launch(void* const* d_in, const int* in_sizes, int n_in,
                              void* d_out, int out_size, void* d_ws, size_t ws_size,
                              hipStream_t stream) {
    const float* x        = (const float*)d_in[0];
    const int*   ei       = (const int*)d_in[1];
    const int*   pos_ei   = (const int*)d_in[3];
    const int*   neg_ei   = (const int*)d_in[4];
    const float* W1       = (const float*)d_in[5];
    const float* att_src1 = (const float*)d_in[6];
    const float* att_dst1 = (const float*)d_in[7];
    const float* b1       = (const float*)d_in[8];
    const float* W2       = (const float*)d_in[9];
    const float* att_src2 = (const float*)d_in[10];
    const float* att_dst2 = (const float*)d_in[11];
    const float* b2       = (const float*)d_in[12];
    const float* lw       = (const float*)d_in[13];
    const float* lb       = (const float*)d_in[14];
    float* out = (float*)d_out;

    char* ws = (char*)d_ws;
    size_t o = 0;
    auto alloc = [&](size_t bytes) -> char* {
        char* p = ws + o;
        o += (bytes + 511) & ~(size_t)511;
        return p;
    };
    unsigned char* xw1q = (unsigned char*)alloc((size_t)N_NODES * 128);   // int8 table
    float*    asp1  = (float*)alloc((size_t)N_NODES * 4 * 4);   // (as0, as1, scl, -)
    float*    ad1   = (float*)alloc((size_t)N_NODES * 2 * 4);
    float*    asp2  = (float*)alloc((size_t)N_NODES * 4 * 4);   // (as2, p1, p2, ad2)
    float*    cvec  = (float*)alloc(512);
    float*    u     = (float*)alloc((size_t)N_NODES * 4);
    float*    v     = (float*)alloc((size_t)N_NODES * 4);
    int*      off   = (int*)alloc((size_t)(N_NODES + 1) * 4);
    int*      hist  = (int*)alloc((size_t)NTOT * 4);
    int*      rowscan = (int*)alloc((size_t)NTOT * 4);
    int*      binsum  = (int*)alloc(256 * 4);
    int*      binoff  = (int*)alloc(256 * 4);
    unsigned* binned= (unsigned*)alloc((size_t)EP * 4);
    int*      csr   = (int*)alloc((size_t)EP * 4);
    _Float16* W1T   = (_Float16*)alloc((size_t)144 * 128 * 2);  // 128 cols + 4 att cols + 12 zero
    _Float16* W2T   = (_Float16*)alloc((size_t)4 * 128 * 2);    // 4 folded cols

    prep_kernel<<<75, 256, 0, stream>>>(W1, W2, att_src1, att_dst1, att_src2, att_dst2,
                                        b2, lw, W1T, W2T, cvec);
    hist_kernel<<<NB2, 256, 0, stream>>>(ei, hist);
    scanA_kernel<<<NBIN, 256, 0, stream>>>(hist, rowscan, binsum);
    scanB_kernel<<<1, 256, 0, stream>>>(binsum, binoff);
    scatterbin_kernel<<<NB2, 256, 0, stream>>>(ei, rowscan, binoff, binned);
    binsort_kernel<<<NBIN, 1024, 0, stream>>>(binned, binoff, off, csr);
    gemm1_kernel<<<(N_NODES + 63) / 64, 256, 0, stream>>>(x, W1T, xw1q, asp1, ad1);
    agg1_kernel<<<N_NODES / 16, 256, 0, stream>>>(off, csr, asp1, ad1, xw1q, b1, W2T, asp2);
    agg2_kernel<<<N_NODES / 16, 256, 0, stream>>>(off, csr, asp2, cvec, u, v);
    decode_kernel<<<(2 * P_CAND + 255) / 256, 256, 0, stream>>>(pos_ei, neg_ei, u, v, lb, out);
}